// Round 16
// baseline (347.883 us; speedup 1.0000x reference)
//
#include <hip/hip_runtime.h>
#include <math.h>

#define Bn   4
#define Tn   2048
#define Dn   1024
#define Hn   4
#define DKn  128
#define DVn  256
#define KDn  512
#define VDn  1024
#define NROWS 8192
#define NCC  32
#define CLEN 64
#define LOG_T_REF_F 6.2383246250395075f

using bf16x8 = __attribute__((ext_vector_type(8))) short;
using f32x4  = __attribute__((ext_vector_type(4))) float;

__device__ __forceinline__ float softplus_f(float x) {
    return fmaxf(x, 0.0f) + log1pf(expf(-fabsf(x)));
}
__device__ __forceinline__ ushort f2bf(float f) {
    unsigned u = __float_as_uint(f);
    u = (u + 0x7fffu + ((u >> 16) & 1u)) >> 16;
    return (ushort)u;
}
__device__ __forceinline__ float bf2f(ushort u) {
    return __uint_as_float((unsigned)u << 16);
}
__device__ __forceinline__ void gload16(const void* g, void* l) {
    __builtin_amdgcn_global_load_lds(
        (const __attribute__((address_space(1))) unsigned*)g,
        (__attribute__((address_space(3))) unsigned*)l, 16, 0, 0);
}

// ---------- fused fp32 -> bf16 cast over 7 segments ----------
struct CastArgs {
    const float* src[7];
    ushort* dst[7];
    int cum[8];
};
__global__ __launch_bounds__(256) void cast_all(CastArgs a) {
    const int total = a.cum[7];
    for (int i = blockIdx.x * 256 + threadIdx.x; i < total; i += gridDim.x * 256) {
        int s = 0;
        #pragma unroll
        for (int k = 1; k < 7; ++k) s += (i >= a.cum[k]) ? 1 : 0;
        const int off = i - a.cum[s];
        float4 v = *(const float4*)&a.src[s][(size_t)off * 4];
        ushort4 u;
        u.x = f2bf(v.x); u.y = f2bf(v.y); u.z = f2bf(v.z); u.w = f2bf(v.w);
        *(ushort4*)&a.dst[s][(size_t)off * 4] = u;
    }
}

// ---------- bf16 MFMA GEMM, BK=64, XCD col-major mapping (B-panel L2-resident) ----------
// A[8192 x 1024] @ Bw[NX*128 x 1024]^T, fp32 accumulate. Grid = NX*64 blocks.
// Per XCD: contiguous l-range decomposed COLUMN-major (bx = l/64, by = l%64) so each
// XCD holds a ~0.5-1MB B-panel in its L2 and streams all 64 A row-groups through it.
// MODE 0: plain fp32 -> C [.][1024]
// MODE 1 (fused projection, NX=28, weights q|k|a|v|g concatenated):
//   col0 <  1024 : qk fp32 (cols<512 scaled by DK^-0.5)
//   col0 <  1536 : gate transform -> Eo [.][512] (LOG decay gk <= 0)
//   else         : cv=col0-1536; cv<1024 -> Cv (v fp32); else -> C2 (g bf16)
template<int MODE, int NX>
__global__ __launch_bounds__(256) void mm3(const ushort* __restrict__ A,
    const ushort* __restrict__ Bw, float* __restrict__ C,
    float* __restrict__ Cv, ushort* __restrict__ C2, float* __restrict__ Eo,
    const float* __restrict__ dt_bias, const float* __restrict__ A_log_base,
    const float* __restrict__ A_log_delta)
{
    __shared__ __align__(16) ushort As[8][128][8];   // 16KB: k-slot s = k in [s*8, s*8+8)
    __shared__ __align__(16) ushort Bs[8][128][8];
    const int raw = blockIdx.x;
    const int nwg = NX * 64;
    const int l = (raw & 7) * (nwg >> 3) + (raw >> 3);   // XCD-chunked remap
    const int bx = l / 64, by = l % 64;                  // col-major: B-panel per XCD
    const int tid = threadIdx.x;
    const int lane = tid & 63, w = tid >> 6;
    const int l15 = lane & 15, lg = lane >> 4;
    const int wr = (w >> 1) << 6, wc = (w & 1) << 6;
    const int row0 = by << 7, col0 = bx << 7;

    const ushort* A0 = A  + (size_t)(row0 + lane) * Dn + w * 8;
    const ushort* A1 = A  + (size_t)(row0 + 64 + lane) * Dn + w * 8;
    const ushort* B0 = Bw + (size_t)(col0 + lane) * Dn + w * 8;
    const ushort* B1 = Bw + (size_t)(col0 + 64 + lane) * Dn + w * 8;

    f32x4 acc[4][4];
    #pragma unroll
    for (int m = 0; m < 4; ++m)
        #pragma unroll
        for (int n = 0; n < 4; ++n)
            acc[m][n] = (f32x4){0.f, 0.f, 0.f, 0.f};

    for (int kt = 0; kt < Dn; kt += 64) {
        __syncthreads();
        // wave w stages slots w and w+4 (k offsets w*8 and w*8+32), both row halves
        gload16(A0 + kt,      &As[w][0][0]);
        gload16(A0 + kt + 32, &As[w + 4][0][0]);
        gload16(A1 + kt,      &As[w][64][0]);
        gload16(A1 + kt + 32, &As[w + 4][64][0]);
        gload16(B0 + kt,      &Bs[w][0][0]);
        gload16(B0 + kt + 32, &Bs[w + 4][0][0]);
        gload16(B1 + kt,      &Bs[w][64][0]);
        gload16(B1 + kt + 32, &Bs[w + 4][64][0]);
        __syncthreads();
        #pragma unroll
        for (int ks = 0; ks < 2; ++ks) {
            bf16x8 af[4], bv[4];
            #pragma unroll
            for (int m = 0; m < 4; ++m)
                af[m] = *(const bf16x8*)&As[ks * 4 + lg][wr + m * 16 + l15][0];
            #pragma unroll
            for (int n = 0; n < 4; ++n)
                bv[n] = *(const bf16x8*)&Bs[ks * 4 + lg][wc + n * 16 + l15][0];
            #pragma unroll
            for (int m = 0; m < 4; ++m)
                #pragma unroll
                for (int n = 0; n < 4; ++n)
                    acc[m][n] = __builtin_amdgcn_mfma_f32_16x16x32_bf16(af[m], bv[n], acc[m][n], 0, 0, 0);
        }
    }

    if (MODE == 1 && col0 >= 1024 && col0 < 1536) {
        // gate-transform epilogue -> LOG decay gk (<= 0)
        const float base_ = A_log_base[0];
        const float s0 = softplus_f(A_log_delta[0]);
        const float s1 = softplus_f(A_log_delta[1]);
        const float s2 = softplus_f(A_log_delta[2]);
        const float c3 = s0 + s1 + s2;
        const float mg = c3 * (1.0f / 3.0f);
        float pf[4][4];
        #pragma unroll
        for (int m = 0; m < 4; ++m) {
            const int row = row0 + wr + m * 16 + lg * 4;
            #pragma unroll
            for (int r = 0; r < 4; ++r) {
                const int t = (row + r) & (Tn - 1);
                pf[m][r] = logf((float)(t + 1));
            }
        }
        #pragma unroll
        for (int n = 0; n < 4; ++n) {
            const int dk = col0 - 1024 + wc + n * 16 + l15;   // 0..511
            const int h = dk >> 7;
            const float cumh = (h == 0) ? 0.f : (h == 1) ? s0 : (h == 2) ? s0 + s1 : c3;
            float alpha = (float)(3 - h) * (1.0f / 3.0f)
                        + (cumh - (float)h * mg) * (1.0f / LOG_T_REF_F);
            alpha = fminf(fmaxf(alpha, 0.0f), 1.0f);
            const float expA = expf(base_ + cumh);
            const float db = dt_bias[dk];
            #pragma unroll
            for (int m = 0; m < 4; ++m) {
                const int row = row0 + wr + m * 16 + lg * 4;
                #pragma unroll
                for (int r = 0; r < 4; ++r) {
                    const float p = expf(-alpha * pf[m][r]);
                    Eo[(size_t)(row + r) * KDn + dk] =
                        -expA * softplus_f(acc[m][n][r] + db) * p;
                }
            }
        }
    } else if (MODE == 1 && col0 >= 1536) {
        const int cv0 = col0 - 1536;
        if (cv0 < 1024) {   // v fp32
            #pragma unroll
            for (int m = 0; m < 4; ++m) {
                const int row = row0 + wr + m * 16 + lg * 4;
                #pragma unroll
                for (int n = 0; n < 4; ++n) {
                    const int col = cv0 + wc + n * 16 + l15;
                    #pragma unroll
                    for (int r = 0; r < 4; ++r)
                        Cv[(size_t)(row + r) * 1024 + col] = acc[m][n][r];
                }
            }
        } else {            // g bf16
            #pragma unroll
            for (int m = 0; m < 4; ++m) {
                const int row = row0 + wr + m * 16 + lg * 4;
                #pragma unroll
                for (int n = 0; n < 4; ++n) {
                    const int col = cv0 - 1024 + wc + n * 16 + l15;
                    #pragma unroll
                    for (int r = 0; r < 4; ++r)
                        C2[(size_t)(row + r) * 1024 + col] = f2bf(acc[m][n][r]);
                }
            }
        }
    } else {
        const float s = (MODE == 1 && col0 < 512) ? 0.08838834764831845f : 1.0f;
        #pragma unroll
        for (int m = 0; m < 4; ++m) {
            const int row = row0 + wr + m * 16 + lg * 4;
            #pragma unroll
            for (int n = 0; n < 4; ++n) {
                const int col = col0 + wc + n * 16 + l15;
                #pragma unroll
                for (int r = 0; r < 4; ++r)
                    C[(size_t)(row + r) * 1024 + col] = acc[m][n][r] * s;
            }
        }
    }
}

// ---------- chunked GLA, log-space attention form (all exp args <= 0) ----------
__global__ __launch_bounds__(1024) void gla_chunk(
    float* qk, const float* __restrict__ Gb, const float* __restrict__ vb,
    float* __restrict__ o, float* __restrict__ Sl, float* __restrict__ Dc)
{
    extern __shared__ __align__(16) char smem[];
    float*  g    = (float*)smem;
    ushort* qraw = (ushort*)(smem + 33792);
    ushort* kraw = (ushort*)(smem + 51200);
    ushort* Qb   = (ushort*)(smem + 68608);
    ushort* Koff = (ushort*)(smem + 86016);
    ushort* KhT  = (ushort*)(smem + 112128);
    ushort* At   = (ushort*)(smem + 130560);
    ushort* VT   = (ushort*)smem;            // overlay (phase >= 4)
    float*  qsum = (float*)(smem + 86016);   // phase-1 temp inside Koff region

    const int bid = blockIdx.x;
    const int co = bid >> 4, bh = bid & 15;
    const int b = bh >> 2, h = bh & 3;
    const int tid = threadIdx.x;
    const int w = tid >> 6, lane = tid & 63;
    const int l15 = lane & 15, lg = lane >> 4;
    const size_t rowbase = (size_t)(b * Tn + co * CLEN);

    // ---- phase 1: inclusive cumsum of gk -> g[64][132] ----
    float c16[16];
    int dk1 = 0, qr1 = 0;
    if (tid < 512) {
        dk1 = tid & 127; qr1 = tid >> 7;
        const float* gp = Gb + (rowbase + qr1 * 16) * 512 + h * 128 + dk1;
        float run = 0.f;
        #pragma unroll
        for (int s = 0; s < 16; ++s) { run += gp[(size_t)s * 512]; c16[s] = run; }
        qsum[qr1 * 128 + dk1] = run;
    }
    __syncthreads();
    if (tid < 512) {
        float pre = 0.f;
        for (int r = 0; r < qr1; ++r) pre += qsum[r * 128 + dk1];
        #pragma unroll
        for (int s = 0; s < 16; ++s) g[(qr1 * 16 + s) * 132 + dk1] = c16[s] + pre;
    }
    __syncthreads();

    // ---- phase 2: operand builds (all exp args <= 0) ----
    #pragma unroll
    for (int it = 0; it < 8; ++it) {
        const int idx = tid + it * 1024;
        const int t = idx >> 7, dk = idx & 127;
        const float gi = g[t * 132 + dk];
        const size_t qaddr = (rowbase + t) * 1024 + h * 128 + dk;
        const float qv = qk[qaddr];
        const float gr = (t < 16) ? 0.f : g[(16 * (t >> 4) - 1) * 132 + dk];
        Qb[t * 136 + dk] = f2bf(qv * __expf(gi - gr));
        qraw[t * 136 + dk] = f2bf(qv);
        qk[qaddr] = qv * __expf(gi);           // q~ in place (for fixup)
        const float kv = qk[qaddr + 512];
        kraw[t * 136 + dk] = f2bf(kv);
        KhT[dk * 72 + t] = f2bf(kv * __expf(g[63 * 132 + dk] - gi));
        if (t < 16) Koff[t * 136 + dk]        = f2bf(kv * __expf(g[15 * 132 + dk] - gi));
        if (t < 32) Koff[(16 + t) * 136 + dk] = f2bf(kv * __expf(g[31 * 132 + dk] - gi));
        if (t < 48) Koff[(48 + t) * 136 + dk] = f2bf(kv * __expf(g[47 * 132 + dk] - gi));
    }
    for (int i = tid; i < 2304; i += 1024) ((int*)At)[i] = 0;   // zero At
    if (tid < 128)
        Dc[(co * 16 + bh) * 128 + tid] = __expf(g[63 * 132 + tid]);
    __syncthreads();

    // ---- phase 3: QK -> At ----
    if (w < 6) {            // off-diagonal sub-chunk tiles (MFMA)
        const int Tt[6] = {16, 32, 32, 48, 48, 48};
        const int Ss[6] = { 0,  0, 16,  0, 16, 32};
        const int Kb[6] = { 0, 16, 16, 48, 48, 48};
        const int T = Tt[w], S = Ss[w], KB = Kb[w];
        f32x4 acc = (f32x4){0.f, 0.f, 0.f, 0.f};
        #pragma unroll
        for (int kk = 0; kk < 4; ++kk) {
            bf16x8 a  = *(const bf16x8*)&Qb[(T + l15) * 136 + kk * 32 + lg * 8];
            bf16x8 bb = *(const bf16x8*)&Koff[(KB + S + l15) * 136 + kk * 32 + lg * 8];
            acc = __builtin_amdgcn_mfma_f32_16x16x32_bf16(a, bb, acc, 0, 0, 0);
        }
        #pragma unroll
        for (int r = 0; r < 4; ++r)
            At[(T + lg * 4 + r) * 72 + S + l15] = f2bf(acc[r]);
    } else if (w < 14) {    // diagonal 16x16 blocks (scalar, masked, log-space)
        const int d = (w - 6) >> 1, hf = (w - 6) & 1;
        #pragma unroll
        for (int pp = 0; pp < 2; ++pp) {
            const int p = hf * 128 + pp * 64 + lane;
            const int i_ = p >> 4, j_ = p & 15;
            if (j_ <= i_) {
                const int ti = d * 16 + i_, tj = d * 16 + j_;
                float a = 0.f;
                for (int dk = 0; dk < 128; ++dk) {
                    const float qf = bf2f(qraw[ti * 136 + dk]);
                    const float kf = bf2f(kraw[tj * 136 + dk]);
                    a += qf * kf * __expf(g[ti * 132 + dk] - g[tj * 132 + dk]);
                }
                At[ti * 72 + tj] = f2bf(a);
            }
        }
    }
    __syncthreads();

    // ---- phase 4: V^T build (overlays dead g/qraw region) ----
    {
        const int dv4 = (tid & 63) * 4, tseg = tid >> 6;
        float4 vv[4];
        #pragma unroll
        for (int s = 0; s < 4; ++s)
            vv[s] = *(const float4*)&vb[(rowbase + tseg * 4 + s) * 1024 + h * 256 + dv4];
        const float* vf = (const float*)vv;
        #pragma unroll
        for (int c = 0; c < 4; ++c) {
            int lo = (unsigned)f2bf(vf[0 * 4 + c]) | ((unsigned)f2bf(vf[1 * 4 + c]) << 16);
            int hi = (unsigned)f2bf(vf[2 * 4 + c]) | ((unsigned)f2bf(vf[3 * 4 + c]) << 16);
            *(int2*)((char*)VT + (size_t)(dv4 + c) * 144 + tseg * 8) = make_int2(lo, hi);
        }
    }
    __syncthreads();

    // ---- phase 5: PV (o intra) + state S_local (MFMA) ----
    float* sp = Sl + (((size_t)co * 16 + bh) << 15);
    for (int id = w; id < 192; id += 16) {
        if (id < 64) {
            const int mt = id >> 4, nt = id & 15;
            f32x4 acc = (f32x4){0.f, 0.f, 0.f, 0.f};
            #pragma unroll
            for (int kk = 0; kk < 2; ++kk) {
                bf16x8 a  = *(const bf16x8*)&At[(mt * 16 + l15) * 72 + kk * 32 + lg * 8];
                bf16x8 bb = *(const bf16x8*)&VT[(nt * 16 + l15) * 72 + kk * 32 + lg * 8];
                acc = __builtin_amdgcn_mfma_f32_16x16x32_bf16(a, bb, acc, 0, 0, 0);
            }
            #pragma unroll
            for (int r = 0; r < 4; ++r)
                o[(rowbase + mt * 16 + lg * 4 + r) * 1024 + h * 256 + nt * 16 + l15] = acc[r];
        } else {
            const int sid = id - 64;
            const int mt = sid >> 4, nt = sid & 15;
            f32x4 acc = (f32x4){0.f, 0.f, 0.f, 0.f};
            #pragma unroll
            for (int kk = 0; kk < 2; ++kk) {
                bf16x8 a  = *(const bf16x8*)&KhT[(mt * 16 + l15) * 72 + kk * 32 + lg * 8];
                bf16x8 bb = *(const bf16x8*)&VT[(nt * 16 + l15) * 72 + kk * 32 + lg * 8];
                acc = __builtin_amdgcn_mfma_f32_16x16x32_bf16(a, bb, acc, 0, 0, 0);
            }
            #pragma unroll
            for (int r = 0; r < 4; ++r)
                sp[(size_t)(mt * 16 + lg * 4 + r) * 256 + nt * 16 + l15] = acc[r];
        }
    }
}

// sequential chunk combine (32 chunks): overwrite Sl[c] with chunk-c START state
__global__ __launch_bounds__(256) void combine(float* __restrict__ Sl,
                                               const float* __restrict__ Dc) {
    const int bh = blockIdx.y;
    const int e4 = blockIdx.x * 256 + threadIdx.x;
    const int dk = e4 >> 6;
    float4 s = make_float4(0.f, 0.f, 0.f, 0.f);
    #pragma unroll 4
    for (int c = 0; c < NCC; ++c) {
        float4* p = (float4*)(Sl + (((size_t)c * 16 + bh) << 15)) + e4;
        float4 local = *p;
        const float d = Dc[(c * 16 + bh) * DKn + dk];
        *p = s;
        s.x = s.x * d + local.x;  s.y = s.y * d + local.y;
        s.z = s.z * d + local.z;  s.w = s.w * d + local.w;
    }
}

// inter-chunk correction: o[t][dv] += sum_dk q~[t][dk] * S_start[dk][dv]
__global__ __launch_bounds__(256, 4) void fixup(const float* __restrict__ qt,
    const float* __restrict__ Sl, float* __restrict__ o)
{
    __shared__ __align__(16) float Aq[16][68];
    __shared__ __align__(16) float Bs[16][68];
    const int raw = blockIdx.x;
    const int l = (raw & 7) * 256 + (raw >> 3);
    const int dvt = l & 3, bh = (l >> 2) & 15, co = l >> 6;
    const int b = bh >> 2, h = bh & 3;
    const int tid = threadIdx.x;
    const int tx = tid & 15, ty = tid >> 4;
    const int t0 = co * CLEN;
    const int dv0 = dvt * 64;

    const float* qbase = qt + (size_t)(b * Tn + t0) * 1024 + h * 128;
    const float* sbase = Sl + (((size_t)co * 16 + bh) << 15) + dv0;

    float acc[4][4] = {};
    for (int k0 = 0; k0 < DKn; k0 += 16) {
        __syncthreads();
        {
            const int t = tid >> 2, kk4 = (tid & 3) << 2;
            float4 a = *(const float4*)&qbase[(size_t)t * 1024 + k0 + kk4];
            Aq[kk4 + 0][t] = a.x; Aq[kk4 + 1][t] = a.y;
            Aq[kk4 + 2][t] = a.z; Aq[kk4 + 3][t] = a.w;
        }
        {
            const int dk = tid >> 4, dvq = (tid & 15) << 2;
            *(float4*)&Bs[dk][dvq] = *(const float4*)&sbase[(size_t)(k0 + dk) * 256 + dvq];
        }
        __syncthreads();
        #pragma unroll
        for (int kk = 0; kk < 16; ++kk) {
            float4 a  = *(const float4*)&Aq[kk][ty * 4];
            float4 bv = *(const float4*)&Bs[kk][tx * 4];
            float ar[4] = {a.x, a.y, a.z, a.w};
            float br[4] = {bv.x, bv.y, bv.z, bv.w};
            #pragma unroll
            for (int i = 0; i < 4; ++i)
                #pragma unroll
                for (int j = 0; j < 4; ++j)
                    acc[i][j] += ar[i] * br[j];
        }
    }
    float* obp = o + (size_t)(b * Tn + t0) * 1024 + h * 256 + dv0;
    #pragma unroll
    for (int i = 0; i < 4; ++i) {
        float* row = obp + (size_t)(ty * 4 + i) * 1024 + tx * 4;
        float4 c = *(float4*)row;
        c.x += acc[i][0]; c.y += acc[i][1];
        c.z += acc[i][2]; c.w += acc[i][3];
        *(float4*)row = c;
    }
}

// ---------- RMSNorm + swish gate (g in bf16) -> bf16 ----------
__global__ __launch_bounds__(256) void rms_gate(const float* __restrict__ o,
    const ushort* __restrict__ gbf, const float* __restrict__ wt,
    ushort* __restrict__ obf)
{
    const int tid = threadIdx.x;
    const int w = tid >> 6, lane = tid & 63;
    const int row = blockIdx.x * 4 + w;
    const int n = row >> 2, h = row & 3;
    const size_t ob_base = (size_t)n * VDn + h * DVn + lane * 4;

    float4 o4 = *(const float4*)&o[ob_base];
    float ss = o4.x*o4.x + o4.y*o4.y + o4.z*o4.z + o4.w*o4.w;
    #pragma unroll
    for (int m = 1; m < 64; m <<= 1) ss += __shfl_xor(ss, m);
    const float r = rsqrtf(ss * (1.0f / DVn) + 1e-5f);

    ushort4 gu = *(const ushort4*)&gbf[ob_base];
    float gx = bf2f(gu.x), gy = bf2f(gu.y), gz = bf2f(gu.z), gw = bf2f(gu.w);
    float4 w4 = *(const float4*)&wt[h * DVn + lane * 4];
    ushort4 u;
    u.x = f2bf(o4.x * r * w4.x * (gx / (1.0f + expf(-gx))));
    u.y = f2bf(o4.y * r * w4.y * (gy / (1.0f + expf(-gy))));
    u.z = f2bf(o4.z * r * w4.z * (gz / (1.0f + expf(-gz))));
    u.w = f2bf(o4.w * r * w4.w * (gw / (1.0f + expf(-gw))));
    *(ushort4*)&obf[ob_base] = u;
}

extern "C" void kernel_launch(void* const* d_in, const int* in_sizes, int n_in,
                              void* d_out, int out_size, void* d_ws, size_t ws_size,
                              hipStream_t stream) {
    const float* hs          = (const float*)d_in[0];
    const float* Wq          = (const float*)d_in[1];
    const float* Wk          = (const float*)d_in[2];
    const float* Wv          = (const float*)d_in[3];
    const float* Wg          = (const float*)d_in[4];
    const float* Wa          = (const float*)d_in[5];
    const float* Wo          = (const float*)d_in[6];
    const float* A_log_base  = (const float*)d_in[7];
    const float* A_log_delta = (const float*)d_in[8];
    const float* dt_bias     = (const float*)d_in[9];
    const float* gnw         = (const float*)d_in[10];
    float* out = (float*)d_out;

    char* ws = (char*)d_ws;
    float*  qk   = (float*)(ws);                           // 32MB [8192][1024] q|k (q~ in place)
    float*  vb   = (float*)(ws + ((size_t)32  << 20));     // 32MB [8192][1024] v
    float*  Gbuf = (float*)(ws + ((size_t)64  << 20));     // 16MB [8192][512] log-decay
    float*  Sl   = (float*)(ws + ((size_t)80  << 20));     // 64MB [32][16][128][256]
    float*  ob   = (float*)(ws + ((size_t)144 << 20));     // 32MB [8192][1024]
    ushort* hsb  = (ushort*)(ws + ((size_t)144 << 20));    // 16MB overlay on ob
    ushort* gbf  = (ushort*)(ws + ((size_t)176 << 20));    // 16MB [8192][1024] g bf16
    ushort* Wcat = (ushort*)(ws + ((size_t)192 << 20));    //  7MB [3584][1024] q|k|a|v|g
    ushort* Wob  = (ushort*)(ws + ((size_t)199 << 20));    //  2MB
    float*  Dc   = (float*)(ws + ((size_t)201 << 20));     // 256KB [32*16][128]
    ushort* obf  = (ushort*)qk;                            // reuse qk after fixup

    // fused casts (weights concatenated q|k|a|v|g)
    CastArgs ca;
    ca.src[0] = hs; ca.src[1] = Wq; ca.src[2] = Wk; ca.src[3] = Wa;
    ca.src[4] = Wv; ca.src[5] = Wg; ca.src[6] = Wo;
    ca.dst[0] = hsb;
    ca.dst[1] = Wcat;
    ca.dst[2] = Wcat + (size_t)512 * 1024;
    ca.dst[3] = Wcat + (size_t)1024 * 1024;
    ca.dst[4] = Wcat + (size_t)1536 * 1024;
    ca.dst[5] = Wcat + (size_t)2560 * 1024;
    ca.dst[6] = Wob;
    const int n4s[7] = {NROWS * Dn / 4, KDn * Dn / 4, KDn * Dn / 4, KDn * Dn / 4,
                        VDn * Dn / 4, VDn * Dn / 4, VDn * Dn / 4};
    ca.cum[0] = 0;
    for (int i = 0; i < 7; ++i) ca.cum[i + 1] = ca.cum[i] + n4s[i];
    cast_all<<<2048, 256, 0, stream>>>(ca);

    // fused projection GEMM: q|k -> qk, a -> Gbuf (log decay), v -> vb, g -> gbf
    mm3<1,28><<<1792, 256, 0, stream>>>(hsb, Wcat, qk, vb, gbf, Gbuf,
                                        dt_bias, A_log_base, A_log_delta);

    // chunked recurrence: log-space attention form
    (void)hipFuncSetAttribute((const void*)gla_chunk,
                              hipFuncAttributeMaxDynamicSharedMemorySize, 139776);
    gla_chunk<<<512, 1024, 139776, stream>>>(qk, Gbuf, vb, ob, Sl, Dc);
    combine<<<dim3(32, 16), 256, 0, stream>>>(Sl, Dc);
    fixup<<<2048, 256, 0, stream>>>(qk, Sl, ob);

    // epilogue
    rms_gate<<<NROWS * Hn / 4, 256, 0, stream>>>(ob, gbf, gnw, obf);
    mm3<0,8><<<512, 256, 0, stream>>>(obf, Wob, out, nullptr, nullptr, nullptr,
                                      nullptr, nullptr, nullptr);
}

// Round 17
// 310.711 us; speedup vs baseline: 1.1196x; 1.1196x over previous
//
#include <hip/hip_runtime.h>
#include <math.h>

#define Bn   4
#define Tn   2048
#define Dn   1024
#define Hn   4
#define DKn  128
#define DVn  256
#define KDn  512
#define VDn  1024
#define NROWS 8192
#define NCC  32
#define CLEN 64
#define LOG_T_REF_F 6.2383246250395075f

using bf16x8 = __attribute__((ext_vector_type(8))) short;
using f32x4  = __attribute__((ext_vector_type(4))) float;

__device__ __forceinline__ float softplus_f(float x) {
    return fmaxf(x, 0.0f) + log1pf(expf(-fabsf(x)));
}
__device__ __forceinline__ ushort f2bf(float f) {
    unsigned u = __float_as_uint(f);
    u = (u + 0x7fffu + ((u >> 16) & 1u)) >> 16;
    return (ushort)u;
}
__device__ __forceinline__ float bf2f(ushort u) {
    return __uint_as_float((unsigned)u << 16);
}
__device__ __forceinline__ void gload16(const void* g, void* l) {
    __builtin_amdgcn_global_load_lds(
        (const __attribute__((address_space(1))) unsigned*)g,
        (__attribute__((address_space(3))) unsigned*)l, 16, 0, 0);
}

// ---------- fused fp32 -> bf16 cast over 7 segments ----------
struct CastArgs {
    const float* src[7];
    ushort* dst[7];
    int cum[8];
};
__global__ __launch_bounds__(256) void cast_all(CastArgs a) {
    const int total = a.cum[7];
    for (int i = blockIdx.x * 256 + threadIdx.x; i < total; i += gridDim.x * 256) {
        int s = 0;
        #pragma unroll
        for (int k = 1; k < 7; ++k) s += (i >= a.cum[k]) ? 1 : 0;
        const int off = i - a.cum[s];
        float4 v = *(const float4*)&a.src[s][(size_t)off * 4];
        ushort4 u;
        u.x = f2bf(v.x); u.y = f2bf(v.y); u.z = f2bf(v.z); u.w = f2bf(v.w);
        *(ushort4*)&a.dst[s][(size_t)off * 4] = u;
    }
}

// ---------- 256x256-tile, BK=64, double-buffered 2-phase fused projection GEMM ----------
// A[8192 x 1024] @ Wcat[3584 x 1024]^T. 512 threads, 8 waves (2Mx4N), wave owns 128x64.
// LDS: 2 bufs x (A[8][256][8] + B[8][256][8]) = 2 x 64KB = 128KB, UNPADDED (slot
// stride 4096B == 0 mod 128B: the [slot][row][8] layout is conflict-free for the
// 16-lane x 16B consecutive ds_read_b128 pattern — measured 0 conflicts in R14).
// Row-major in-XCD mapping: A-panel (4x256 rows = 2MB) L2-resident, B streamed.
// Epilogue by col0: <1024 qk fp32 (cols<512 scaled); <1536 gate->log decay Eo;
// <2560 v fp32; else g bf16.
template<int NX>   // NX = N/256 = 14
__global__ __launch_bounds__(512) void mm_big(const ushort* __restrict__ A,
    const ushort* __restrict__ Bw, float* __restrict__ C,
    float* __restrict__ Cv, ushort* __restrict__ C2, float* __restrict__ Eo,
    const float* __restrict__ dt_bias, const float* __restrict__ A_log_base,
    const float* __restrict__ A_log_delta)
{
    extern __shared__ __align__(16) char smem2[];
    ushort* sm = (ushort*)smem2;
    const int raw = blockIdx.x;
    const int nwg = NX * 32;                       // 448
    const int l = (raw & 7) * (nwg >> 3) + (raw >> 3);
    const int bx = l % NX, by = l / NX;            // row-major: A-panel per XCD
    const int tid = threadIdx.x;
    const int w = tid >> 6, lane = tid & 63;
    const int l15 = lane & 15, lg = lane >> 4;
    const int wr = w >> 2, wc = w & 3;
    const int row0 = by << 8, col0 = bx << 8;

    const ushort* Asrc = A  + (size_t)(row0 + lane) * Dn + w * 8;
    const ushort* Bsrc = Bw + (size_t)(col0 + lane) * Dn + w * 8;

    f32x4 acc[8][4];
    #pragma unroll
    for (int m = 0; m < 8; ++m)
        #pragma unroll
        for (int n = 0; n < 4; ++n)
            acc[m][n] = (f32x4){0.f, 0.f, 0.f, 0.f};

    // stage K-tile kt into buffer buf: wave w stages A slot w + B slot w (4 row-groups each)
    #define STAGE(buf, kt)                                                        \
    {                                                                             \
        ushort* ab_ = sm + (buf) * 32768 + w * 2048;                              \
        ushort* bb_ = ab_ + 16384;                                                \
        _Pragma("unroll")                                                         \
        for (int g_ = 0; g_ < 4; ++g_) {                                          \
            gload16(Asrc + (size_t)g_ * 64 * Dn + (kt), ab_ + g_ * 512);          \
            gload16(Bsrc + (size_t)g_ * 64 * Dn + (kt), bb_ + g_ * 512);          \
        }                                                                         \
    }

    STAGE(0, 0)
    for (int it = 0; it < 16; ++it) {
        const int cur = it & 1;
        if (it < 15) {
            STAGE(cur ^ 1, (it + 1) * 64)
            asm volatile("s_waitcnt vmcnt(8)" ::: "memory");   // cur tile landed
        } else {
            asm volatile("s_waitcnt vmcnt(0)" ::: "memory");
        }
        asm volatile("s_barrier" ::: "memory");                 // all waves: cur ready
        const ushort* ab = sm + cur * 32768;
        const ushort* bb = ab + 16384;
        #pragma unroll
        for (int ks = 0; ks < 2; ++ks) {
            bf16x8 af[8], bv[4];
            #pragma unroll
            for (int m = 0; m < 8; ++m)
                af[m] = *(const bf16x8*)(ab + (ks * 4 + lg) * 2048
                                            + (wr * 128 + m * 16 + l15) * 8);
            #pragma unroll
            for (int n = 0; n < 4; ++n)
                bv[n] = *(const bf16x8*)(bb + (ks * 4 + lg) * 2048
                                            + (wc * 64 + n * 16 + l15) * 8);
            #pragma unroll
            for (int m = 0; m < 8; ++m)
                #pragma unroll
                for (int n = 0; n < 4; ++n)
                    acc[m][n] = __builtin_amdgcn_mfma_f32_16x16x32_bf16(af[m], bv[n], acc[m][n], 0, 0, 0);
        }
        asm volatile("s_barrier" ::: "memory");                 // cur free for overwrite
    }
    #undef STAGE

    if (col0 >= 1024 && col0 < 1536) {
        // gate-transform epilogue -> LOG decay gk (<= 0)
        const float base_ = A_log_base[0];
        const float s0 = softplus_f(A_log_delta[0]);
        const float s1 = softplus_f(A_log_delta[1]);
        const float s2 = softplus_f(A_log_delta[2]);
        const float c3 = s0 + s1 + s2;
        const float mg = c3 * (1.0f / 3.0f);
        #pragma unroll
        for (int m = 0; m < 8; ++m) {
            const int row = row0 + wr * 128 + m * 16 + lg * 4;
            float pf[4];
            #pragma unroll
            for (int r = 0; r < 4; ++r) {
                const int t = (row + r) & (Tn - 1);
                pf[r] = logf((float)(t + 1));
            }
            #pragma unroll
            for (int n = 0; n < 4; ++n) {
                const int dk = col0 - 1024 + wc * 64 + n * 16 + l15;   // 0..511
                const int h = dk >> 7;
                const float cumh = (h == 0) ? 0.f : (h == 1) ? s0 : (h == 2) ? s0 + s1 : c3;
                float alpha = (float)(3 - h) * (1.0f / 3.0f)
                            + (cumh - (float)h * mg) * (1.0f / LOG_T_REF_F);
                alpha = fminf(fmaxf(alpha, 0.0f), 1.0f);
                const float expA = expf(base_ + cumh);
                const float db = dt_bias[dk];
                #pragma unroll
                for (int r = 0; r < 4; ++r) {
                    const float p = expf(-alpha * pf[r]);
                    Eo[(size_t)(row + r) * KDn + dk] =
                        -expA * softplus_f(acc[m][n][r] + db) * p;
                }
            }
        }
    } else if (col0 >= 2560) {
        // g bf16
        #pragma unroll
        for (int m = 0; m < 8; ++m) {
            const int row = row0 + wr * 128 + m * 16 + lg * 4;
            #pragma unroll
            for (int n = 0; n < 4; ++n) {
                const int col = col0 - 2560 + wc * 64 + n * 16 + l15;
                #pragma unroll
                for (int r = 0; r < 4; ++r)
                    C2[(size_t)(row + r) * 1024 + col] = f2bf(acc[m][n][r]);
            }
        }
    } else if (col0 >= 1536) {
        // v fp32
        #pragma unroll
        for (int m = 0; m < 8; ++m) {
            const int row = row0 + wr * 128 + m * 16 + lg * 4;
            #pragma unroll
            for (int n = 0; n < 4; ++n) {
                const int col = col0 - 1536 + wc * 64 + n * 16 + l15;
                #pragma unroll
                for (int r = 0; r < 4; ++r)
                    Cv[(size_t)(row + r) * 1024 + col] = acc[m][n][r];
            }
        }
    } else {
        // qk fp32 (cols < 512 scaled by DK^-0.5)
        const float s = (col0 < 512) ? 0.08838834764831845f : 1.0f;
        #pragma unroll
        for (int m = 0; m < 8; ++m) {
            const int row = row0 + wr * 128 + m * 16 + lg * 4;
            #pragma unroll
            for (int n = 0; n < 4; ++n) {
                const int col = col0 + wc * 64 + n * 16 + l15;
                #pragma unroll
                for (int r = 0; r < 4; ++r)
                    C[(size_t)(row + r) * 1024 + col] = acc[m][n][r] * s;
            }
        }
    }
}

// ---------- 128x128 bf16 MFMA GEMM (output projection), BK=64, row-major XCD ----------
__global__ __launch_bounds__(256) void mm_out(const ushort* __restrict__ A,
    const ushort* __restrict__ Bw, float* __restrict__ C)
{
    __shared__ __align__(16) ushort As[8][128][8];
    __shared__ __align__(16) ushort Bs[8][128][8];
    const int raw = blockIdx.x;
    const int l = (raw & 7) * 64 + (raw >> 3);
    const int bx = l % 8, by = l / 8;
    const int tid = threadIdx.x;
    const int lane = tid & 63, w = tid >> 6;
    const int l15 = lane & 15, lg = lane >> 4;
    const int wr = (w >> 1) << 6, wc = (w & 1) << 6;
    const int row0 = by << 7, col0 = bx << 7;

    const ushort* A0 = A  + (size_t)(row0 + lane) * Dn + w * 8;
    const ushort* A1 = A  + (size_t)(row0 + 64 + lane) * Dn + w * 8;
    const ushort* B0 = Bw + (size_t)(col0 + lane) * Dn + w * 8;
    const ushort* B1 = Bw + (size_t)(col0 + 64 + lane) * Dn + w * 8;

    f32x4 acc[4][4];
    #pragma unroll
    for (int m = 0; m < 4; ++m)
        #pragma unroll
        for (int n = 0; n < 4; ++n)
            acc[m][n] = (f32x4){0.f, 0.f, 0.f, 0.f};

    for (int kt = 0; kt < Dn; kt += 64) {
        __syncthreads();
        gload16(A0 + kt,      &As[w][0][0]);
        gload16(A0 + kt + 32, &As[w + 4][0][0]);
        gload16(A1 + kt,      &As[w][64][0]);
        gload16(A1 + kt + 32, &As[w + 4][64][0]);
        gload16(B0 + kt,      &Bs[w][0][0]);
        gload16(B0 + kt + 32, &Bs[w + 4][0][0]);
        gload16(B1 + kt,      &Bs[w][64][0]);
        gload16(B1 + kt + 32, &Bs[w + 4][64][0]);
        __syncthreads();
        #pragma unroll
        for (int ks = 0; ks < 2; ++ks) {
            bf16x8 af[4], bv[4];
            #pragma unroll
            for (int m = 0; m < 4; ++m)
                af[m] = *(const bf16x8*)&As[ks * 4 + lg][wr + m * 16 + l15][0];
            #pragma unroll
            for (int n = 0; n < 4; ++n)
                bv[n] = *(const bf16x8*)&Bs[ks * 4 + lg][wc + n * 16 + l15][0];
            #pragma unroll
            for (int m = 0; m < 4; ++m)
                #pragma unroll
                for (int n = 0; n < 4; ++n)
                    acc[m][n] = __builtin_amdgcn_mfma_f32_16x16x32_bf16(af[m], bv[n], acc[m][n], 0, 0, 0);
        }
    }
    #pragma unroll
    for (int m = 0; m < 4; ++m) {
        const int row = row0 + wr + m * 16 + lg * 4;
        #pragma unroll
        for (int n = 0; n < 4; ++n) {
            const int col = col0 + wc + n * 16 + l15;
            #pragma unroll
            for (int r = 0; r < 4; ++r)
                C[(size_t)(row + r) * 1024 + col] = acc[m][n][r];
        }
    }
}

// ---------- chunked GLA, log-space attention form (all exp args <= 0) ----------
__global__ __launch_bounds__(1024) void gla_chunk(
    float* qk, const float* __restrict__ Gb, const float* __restrict__ vb,
    float* __restrict__ o, float* __restrict__ Sl, float* __restrict__ Dc)
{
    extern __shared__ __align__(16) char smem[];
    float*  g    = (float*)smem;
    ushort* qraw = (ushort*)(smem + 33792);
    ushort* kraw = (ushort*)(smem + 51200);
    ushort* Qb   = (ushort*)(smem + 68608);
    ushort* Koff = (ushort*)(smem + 86016);
    ushort* KhT  = (ushort*)(smem + 112128);
    ushort* At   = (ushort*)(smem + 130560);
    ushort* VT   = (ushort*)smem;            // overlay (phase >= 4)
    float*  qsum = (float*)(smem + 86016);   // phase-1 temp inside Koff region

    const int bid = blockIdx.x;
    const int co = bid >> 4, bh = bid & 15;
    const int b = bh >> 2, h = bh & 3;
    const int tid = threadIdx.x;
    const int w = tid >> 6, lane = tid & 63;
    const int l15 = lane & 15, lg = lane >> 4;
    const size_t rowbase = (size_t)(b * Tn + co * CLEN);

    // ---- phase 1: inclusive cumsum of gk -> g[64][132] ----
    float c16[16];
    int dk1 = 0, qr1 = 0;
    if (tid < 512) {
        dk1 = tid & 127; qr1 = tid >> 7;
        const float* gp = Gb + (rowbase + qr1 * 16) * 512 + h * 128 + dk1;
        float run = 0.f;
        #pragma unroll
        for (int s = 0; s < 16; ++s) { run += gp[(size_t)s * 512]; c16[s] = run; }
        qsum[qr1 * 128 + dk1] = run;
    }
    __syncthreads();
    if (tid < 512) {
        float pre = 0.f;
        for (int r = 0; r < qr1; ++r) pre += qsum[r * 128 + dk1];
        #pragma unroll
        for (int s = 0; s < 16; ++s) g[(qr1 * 16 + s) * 132 + dk1] = c16[s] + pre;
    }
    __syncthreads();

    // ---- phase 2: operand builds (all exp args <= 0) ----
    #pragma unroll
    for (int it = 0; it < 8; ++it) {
        const int idx = tid + it * 1024;
        const int t = idx >> 7, dk = idx & 127;
        const float gi = g[t * 132 + dk];
        const size_t qaddr = (rowbase + t) * 1024 + h * 128 + dk;
        const float qv = qk[qaddr];
        const float gr = (t < 16) ? 0.f : g[(16 * (t >> 4) - 1) * 132 + dk];
        Qb[t * 136 + dk] = f2bf(qv * __expf(gi - gr));
        qraw[t * 136 + dk] = f2bf(qv);
        qk[qaddr] = qv * __expf(gi);           // q~ in place (for fixup)
        const float kv = qk[qaddr + 512];
        kraw[t * 136 + dk] = f2bf(kv);
        KhT[dk * 72 + t] = f2bf(kv * __expf(g[63 * 132 + dk] - gi));
        if (t < 16) Koff[t * 136 + dk]        = f2bf(kv * __expf(g[15 * 132 + dk] - gi));
        if (t < 32) Koff[(16 + t) * 136 + dk] = f2bf(kv * __expf(g[31 * 132 + dk] - gi));
        if (t < 48) Koff[(48 + t) * 136 + dk] = f2bf(kv * __expf(g[47 * 132 + dk] - gi));
    }
    for (int i = tid; i < 2304; i += 1024) ((int*)At)[i] = 0;   // zero At
    if (tid < 128)
        Dc[(co * 16 + bh) * 128 + tid] = __expf(g[63 * 132 + tid]);
    __syncthreads();

    // ---- phase 3: QK -> At ----
    if (w < 6) {            // off-diagonal sub-chunk tiles (MFMA)
        const int Tt[6] = {16, 32, 32, 48, 48, 48};
        const int Ss[6] = { 0,  0, 16,  0, 16, 32};
        const int Kb[6] = { 0, 16, 16, 48, 48, 48};
        const int T = Tt[w], S = Ss[w], KB = Kb[w];
        f32x4 acc = (f32x4){0.f, 0.f, 0.f, 0.f};
        #pragma unroll
        for (int kk = 0; kk < 4; ++kk) {
            bf16x8 a  = *(const bf16x8*)&Qb[(T + l15) * 136 + kk * 32 + lg * 8];
            bf16x8 bb = *(const bf16x8*)&Koff[(KB + S + l15) * 136 + kk * 32 + lg * 8];
            acc = __builtin_amdgcn_mfma_f32_16x16x32_bf16(a, bb, acc, 0, 0, 0);
        }
        #pragma unroll
        for (int r = 0; r < 4; ++r)
            At[(T + lg * 4 + r) * 72 + S + l15] = f2bf(acc[r]);
    } else if (w < 14) {    // diagonal 16x16 blocks (scalar, masked, log-space)
        const int d = (w - 6) >> 1, hf = (w - 6) & 1;
        #pragma unroll
        for (int pp = 0; pp < 2; ++pp) {
            const int p = hf * 128 + pp * 64 + lane;
            const int i_ = p >> 4, j_ = p & 15;
            if (j_ <= i_) {
                const int ti = d * 16 + i_, tj = d * 16 + j_;
                float a = 0.f;
                for (int dk = 0; dk < 128; ++dk) {
                    const float qf = bf2f(qraw[ti * 136 + dk]);
                    const float kf = bf2f(kraw[tj * 136 + dk]);
                    a += qf * kf * __expf(g[ti * 132 + dk] - g[tj * 132 + dk]);
                }
                At[ti * 72 + tj] = f2bf(a);
            }
        }
    }
    __syncthreads();

    // ---- phase 4: V^T build (overlays dead g/qraw region) ----
    {
        const int dv4 = (tid & 63) * 4, tseg = tid >> 6;
        float4 vv[4];
        #pragma unroll
        for (int s = 0; s < 4; ++s)
            vv[s] = *(const float4*)&vb[(rowbase + tseg * 4 + s) * 1024 + h * 256 + dv4];
        const float* vf = (const float*)vv;
        #pragma unroll
        for (int c = 0; c < 4; ++c) {
            int lo = (unsigned)f2bf(vf[0 * 4 + c]) | ((unsigned)f2bf(vf[1 * 4 + c]) << 16);
            int hi = (unsigned)f2bf(vf[2 * 4 + c]) | ((unsigned)f2bf(vf[3 * 4 + c]) << 16);
            *(int2*)((char*)VT + (size_t)(dv4 + c) * 144 + tseg * 8) = make_int2(lo, hi);
        }
    }
    __syncthreads();

    // ---- phase 5: PV (o intra) + state S_local (MFMA) ----
    float* sp = Sl + (((size_t)co * 16 + bh) << 15);
    for (int id = w; id < 192; id += 16) {
        if (id < 64) {
            const int mt = id >> 4, nt = id & 15;
            f32x4 acc = (f32x4){0.f, 0.f, 0.f, 0.f};
            #pragma unroll
            for (int kk = 0; kk < 2; ++kk) {
                bf16x8 a  = *(const bf16x8*)&At[(mt * 16 + l15) * 72 + kk * 32 + lg * 8];
                bf16x8 bb = *(const bf16x8*)&VT[(nt * 16 + l15) * 72 + kk * 32 + lg * 8];
                acc = __builtin_amdgcn_mfma_f32_16x16x32_bf16(a, bb, acc, 0, 0, 0);
            }
            #pragma unroll
            for (int r = 0; r < 4; ++r)
                o[(rowbase + mt * 16 + lg * 4 + r) * 1024 + h * 256 + nt * 16 + l15] = acc[r];
        } else {
            const int sid = id - 64;
            const int mt = sid >> 4, nt = sid & 15;
            f32x4 acc = (f32x4){0.f, 0.f, 0.f, 0.f};
            #pragma unroll
            for (int kk = 0; kk < 2; ++kk) {
                bf16x8 a  = *(const bf16x8*)&KhT[(mt * 16 + l15) * 72 + kk * 32 + lg * 8];
                bf16x8 bb = *(const bf16x8*)&VT[(nt * 16 + l15) * 72 + kk * 32 + lg * 8];
                acc = __builtin_amdgcn_mfma_f32_16x16x32_bf16(a, bb, acc, 0, 0, 0);
            }
            #pragma unroll
            for (int r = 0; r < 4; ++r)
                sp[(size_t)(mt * 16 + lg * 4 + r) * 256 + nt * 16 + l15] = acc[r];
        }
    }
}

// sequential chunk combine (32 chunks): overwrite Sl[c] with chunk-c START state
__global__ __launch_bounds__(256) void combine(float* __restrict__ Sl,
                                               const float* __restrict__ Dc) {
    const int bh = blockIdx.y;
    const int e4 = blockIdx.x * 256 + threadIdx.x;
    const int dk = e4 >> 6;
    float4 s = make_float4(0.f, 0.f, 0.f, 0.f);
    #pragma unroll 4
    for (int c = 0; c < NCC; ++c) {
        float4* p = (float4*)(Sl + (((size_t)c * 16 + bh) << 15)) + e4;
        float4 local = *p;
        const float d = Dc[(c * 16 + bh) * DKn + dk];
        *p = s;
        s.x = s.x * d + local.x;  s.y = s.y * d + local.y;
        s.z = s.z * d + local.z;  s.w = s.w * d + local.w;
    }
}

// inter-chunk correction: o[t][dv] += sum_dk q~[t][dk] * S_start[dk][dv]
__global__ __launch_bounds__(256, 4) void fixup(const float* __restrict__ qt,
    const float* __restrict__ Sl, float* __restrict__ o)
{
    __shared__ __align__(16) float Aq[16][68];
    __shared__ __align__(16) float Bs[16][68];
    const int raw = blockIdx.x;
    const int l = (raw & 7) * 256 + (raw >> 3);
    const int dvt = l & 3, bh = (l >> 2) & 15, co = l >> 6;
    const int b = bh >> 2, h = bh & 3;
    const int tid = threadIdx.x;
    const int tx = tid & 15, ty = tid >> 4;
    const int t0 = co * CLEN;
    const int dv0 = dvt * 64;

    const float* qbase = qt + (size_t)(b * Tn + t0) * 1024 + h * 128;
    const float* sbase = Sl + (((size_t)co * 16 + bh) << 15) + dv0;

    float acc[4][4] = {};
    for (int k0 = 0; k0 < DKn; k0 += 16) {
        __syncthreads();
        {
            const int t = tid >> 2, kk4 = (tid & 3) << 2;
            float4 a = *(const float4*)&qbase[(size_t)t * 1024 + k0 + kk4];
            Aq[kk4 + 0][t] = a.x; Aq[kk4 + 1][t] = a.y;
            Aq[kk4 + 2][t] = a.z; Aq[kk4 + 3][t] = a.w;
        }
        {
            const int dk = tid >> 4, dvq = (tid & 15) << 2;
            *(float4*)&Bs[dk][dvq] = *(const float4*)&sbase[(size_t)(k0 + dk) * 256 + dvq];
        }
        __syncthreads();
        #pragma unroll
        for (int kk = 0; kk < 16; ++kk) {
            float4 a  = *(const float4*)&Aq[kk][ty * 4];
            float4 bv = *(const float4*)&Bs[kk][tx * 4];
            float ar[4] = {a.x, a.y, a.z, a.w};
            float br[4] = {bv.x, bv.y, bv.z, bv.w};
            #pragma unroll
            for (int i = 0; i < 4; ++i)
                #pragma unroll
                for (int j = 0; j < 4; ++j)
                    acc[i][j] += ar[i] * br[j];
        }
    }
    float* obp = o + (size_t)(b * Tn + t0) * 1024 + h * 256 + dv0;
    #pragma unroll
    for (int i = 0; i < 4; ++i) {
        float* row = obp + (size_t)(ty * 4 + i) * 1024 + tx * 4;
        float4 c = *(float4*)row;
        c.x += acc[i][0]; c.y += acc[i][1];
        c.z += acc[i][2]; c.w += acc[i][3];
        *(float4*)row = c;
    }
}

// ---------- RMSNorm + swish gate (g in bf16) -> bf16 ----------
__global__ __launch_bounds__(256) void rms_gate(const float* __restrict__ o,
    const ushort* __restrict__ gbf, const float* __restrict__ wt,
    ushort* __restrict__ obf)
{
    const int tid = threadIdx.x;
    const int w = tid >> 6, lane = tid & 63;
    const int row = blockIdx.x * 4 + w;
    const int n = row >> 2, h = row & 3;
    const size_t ob_base = (size_t)n * VDn + h * DVn + lane * 4;

    float4 o4 = *(const float4*)&o[ob_base];
    float ss = o4.x*o4.x + o4.y*o4.y + o4.z*o4.z + o4.w*o4.w;
    #pragma unroll
    for (int m = 1; m < 64; m <<= 1) ss += __shfl_xor(ss, m);
    const float r = rsqrtf(ss * (1.0f / DVn) + 1e-5f);

    ushort4 gu = *(const ushort4*)&gbf[ob_base];
    float gx = bf2f(gu.x), gy = bf2f(gu.y), gz = bf2f(gu.z), gw = bf2f(gu.w);
    float4 w4 = *(const float4*)&wt[h * DVn + lane * 4];
    ushort4 u;
    u.x = f2bf(o4.x * r * w4.x * (gx / (1.0f + expf(-gx))));
    u.y = f2bf(o4.y * r * w4.y * (gy / (1.0f + expf(-gy))));
    u.z = f2bf(o4.z * r * w4.z * (gz / (1.0f + expf(-gz))));
    u.w = f2bf(o4.w * r * w4.w * (gw / (1.0f + expf(-gw))));
    *(ushort4*)&obf[ob_base] = u;
}

extern "C" void kernel_launch(void* const* d_in, const int* in_sizes, int n_in,
                              void* d_out, int out_size, void* d_ws, size_t ws_size,
                              hipStream_t stream) {
    const float* hs          = (const float*)d_in[0];
    const float* Wq          = (const float*)d_in[1];
    const float* Wk          = (const float*)d_in[2];
    const float* Wv          = (const float*)d_in[3];
    const float* Wg          = (const float*)d_in[4];
    const float* Wa          = (const float*)d_in[5];
    const float* Wo          = (const float*)d_in[6];
    const float* A_log_base  = (const float*)d_in[7];
    const float* A_log_delta = (const float*)d_in[8];
    const float* dt_bias     = (const float*)d_in[9];
    const float* gnw         = (const float*)d_in[10];
    float* out = (float*)d_out;

    char* ws = (char*)d_ws;
    float*  qk   = (float*)(ws);                           // 32MB [8192][1024] q|k (q~ in place)
    float*  vb   = (float*)(ws + ((size_t)32  << 20));     // 32MB [8192][1024] v
    float*  Gbuf = (float*)(ws + ((size_t)64  << 20));     // 16MB [8192][512] log-decay
    float*  Sl   = (float*)(ws + ((size_t)80  << 20));     // 64MB [32][16][128][256]
    float*  ob   = (float*)(ws + ((size_t)144 << 20));     // 32MB [8192][1024]
    ushort* hsb  = (ushort*)(ws + ((size_t)144 << 20));    // 16MB overlay on ob
    ushort* gbf  = (ushort*)(ws + ((size_t)176 << 20));    // 16MB [8192][1024] g bf16
    ushort* Wcat = (ushort*)(ws + ((size_t)192 << 20));    //  7MB [3584][1024] q|k|a|v|g
    ushort* Wob  = (ushort*)(ws + ((size_t)199 << 20));    //  2MB
    float*  Dc   = (float*)(ws + ((size_t)201 << 20));     // 256KB [32*16][128]
    ushort* obf  = (ushort*)qk;                            // reuse qk after fixup

    // fused casts (weights concatenated q|k|a|v|g)
    CastArgs ca;
    ca.src[0] = hs; ca.src[1] = Wq; ca.src[2] = Wk; ca.src[3] = Wa;
    ca.src[4] = Wv; ca.src[5] = Wg; ca.src[6] = Wo;
    ca.dst[0] = hsb;
    ca.dst[1] = Wcat;
    ca.dst[2] = Wcat + (size_t)512 * 1024;
    ca.dst[3] = Wcat + (size_t)1024 * 1024;
    ca.dst[4] = Wcat + (size_t)1536 * 1024;
    ca.dst[5] = Wcat + (size_t)2560 * 1024;
    ca.dst[6] = Wob;
    const int n4s[7] = {NROWS * Dn / 4, KDn * Dn / 4, KDn * Dn / 4, KDn * Dn / 4,
                        VDn * Dn / 4, VDn * Dn / 4, VDn * Dn / 4};
    ca.cum[0] = 0;
    for (int i = 0; i < 7; ++i) ca.cum[i + 1] = ca.cum[i] + n4s[i];
    cast_all<<<2048, 256, 0, stream>>>(ca);

    // fused projection GEMM (256^2 2-phase, unpadded LDS): q|k, a->Gbuf, v, g
    (void)hipFuncSetAttribute((const void*)mm_big<14>,
                              hipFuncAttributeMaxDynamicSharedMemorySize, 131072);
    mm_big<14><<<448, 512, 131072, stream>>>(hsb, Wcat, qk, vb, gbf, Gbuf,
                                             dt_bias, A_log_base, A_log_delta);

    // chunked recurrence: log-space attention form
    (void)hipFuncSetAttribute((const void*)gla_chunk,
                              hipFuncAttributeMaxDynamicSharedMemorySize, 139776);
    gla_chunk<<<512, 1024, 139776, stream>>>(qk, Gbuf, vb, ob, Sl, Dc);
    combine<<<dim3(32, 16), 256, 0, stream>>>(Sl, Dc);
    fixup<<<2048, 256, 0, stream>>>(qk, Sl, ob);

    // epilogue
    rms_gate<<<NROWS * Hn / 4, 256, 0, stream>>>(ob, gbf, gnw, obf);
    mm_out<<<512, 256, 0, stream>>>(obf, Wob, out);
}

// Round 19
// 300.667 us; speedup vs baseline: 1.1570x; 1.0334x over previous
//
#include <hip/hip_runtime.h>
#include <math.h>

#define Bn   4
#define Tn   2048
#define Dn   1024
#define Hn   4
#define DKn  128
#define DVn  256
#define KDn  512
#define VDn  1024
#define NROWS 8192
#define NCC  32
#define CLEN 64
#define LOG_T_REF_F 6.2383246250395075f

using bf16x8 = __attribute__((ext_vector_type(8))) short;
using f32x4  = __attribute__((ext_vector_type(4))) float;

__device__ __forceinline__ float softplus_f(float x) {
    return fmaxf(x, 0.0f) + log1pf(expf(-fabsf(x)));
}
__device__ __forceinline__ ushort f2bf(float f) {
    unsigned u = __float_as_uint(f);
    u = (u + 0x7fffu + ((u >> 16) & 1u)) >> 16;
    return (ushort)u;
}
__device__ __forceinline__ float bf2f(ushort u) {
    return __uint_as_float((unsigned)u << 16);
}
__device__ __forceinline__ void gload16(const void* g, void* l) {
    __builtin_amdgcn_global_load_lds(
        (const __attribute__((address_space(1))) unsigned*)g,
        (__attribute__((address_space(3))) unsigned*)l, 16, 0, 0);
}

// ---------- fused fp32 -> bf16 cast over 7 segments ----------
struct CastArgs {
    const float* src[7];
    ushort* dst[7];
    int cum[8];
};
__global__ __launch_bounds__(256) void cast_all(CastArgs a) {
    const int total = a.cum[7];
    for (int i = blockIdx.x * 256 + threadIdx.x; i < total; i += gridDim.x * 256) {
        int s = 0;
        #pragma unroll
        for (int k = 1; k < 7; ++k) s += (i >= a.cum[k]) ? 1 : 0;
        const int off = i - a.cum[s];
        float4 v = *(const float4*)&a.src[s][(size_t)off * 4];
        ushort4 u;
        u.x = f2bf(v.x); u.y = f2bf(v.y); u.z = f2bf(v.z); u.w = f2bf(v.w);
        *(ushort4*)&a.dst[s][(size_t)off * 4] = u;
    }
}

// ---------- 256x256-tile fused projection GEMM, sliced schedule (race-fixed) ----------
// A[8192 x 1024] @ Wcat[3584 x 1024]^T. 512 threads, 8 waves (2Mx4N), wave owns 128x64.
// K in 32 slices of 32; ring of 4 slots/operand (16KB each, [4 ksub][256 row][8] bf16,
// conflict-free). Slice loop: [even S: vmcnt(4) — slices S,S+1 landed] -> s_barrier
// (cross-wave visibility + slot-overwrite safety) -> phase0 {ds_read A-lo+B ||
// STAGE_A(S+3) || lgkmcnt(0) || 16 MFMA} -> phase1 {ds_read A-hi || STAGE_B(S+3) ||
// lgkmcnt(0) || 16 MFMA}. vmcnt never 0 mid-loop (drain at S=30).
// Row-major in-XCD mapping. Accumulation order == R17 (bitwise-identical results).
template<int NX>   // NX = N/256 = 14
__global__ __launch_bounds__(512) void mm_big(const ushort* __restrict__ A,
    const ushort* __restrict__ Bw, float* __restrict__ C,
    float* __restrict__ Cv, ushort* __restrict__ C2, float* __restrict__ Eo,
    const float* __restrict__ dt_bias, const float* __restrict__ A_log_base,
    const float* __restrict__ A_log_delta)
{
    extern __shared__ __align__(16) char smem2[];
    ushort* Ar = (ushort*)smem2;           // 4 slots x 8192 ushorts (16KB each)
    ushort* Br = Ar + 4 * 8192;
    const int raw = blockIdx.x;
    const int nwg = NX * 32;               // 448
    const int l = (raw & 7) * (nwg >> 3) + (raw >> 3);
    const int bx = l % NX, by = l / NX;    // row-major: A-panel per XCD
    const int tid = threadIdx.x;
    const int w = tid >> 6, lane = tid & 63;
    const int l15 = lane & 15, lg = lane >> 4;
    const int wr = w >> 2, wc = w & 3;
    const int row0 = by << 8, col0 = bx << 8;

    // staging assignment: wave w covers ksub = w>>1, rowgroups rg0, rg0+1 (rg0 = (w&1)*2)
    const int ksw = w >> 1;
    const int rg0 = (w & 1) * 2;
    const ushort* Asrc = A  + (size_t)(row0 + rg0 * 64 + lane) * Dn + ksw * 8;
    const ushort* Bsrc = Bw + (size_t)(col0 + rg0 * 64 + lane) * Dn + ksw * 8;
    ushort* Adst0 = Ar + (ksw * 256 + rg0 * 64) * 8;
    ushort* Bdst0 = Br + (ksw * 256 + rg0 * 64) * 8;

#define STAGE_A(S) { ushort* d_ = Adst0 + ((S) & 3) * 8192;                    \
    const ushort* s_ = Asrc + (size_t)(S) * 32;                                \
    gload16(s_, d_); gload16(s_ + (size_t)64 * Dn, d_ + 512); }
#define STAGE_B(S) { ushort* d_ = Bdst0 + ((S) & 3) * 8192;                    \
    const ushort* s_ = Bsrc + (size_t)(S) * 32;                                \
    gload16(s_, d_); gload16(s_ + (size_t)64 * Dn, d_ + 512); }

    f32x4 acc[8][4];
    #pragma unroll
    for (int m = 0; m < 8; ++m)
        #pragma unroll
        for (int n = 0; n < 4; ++n)
            acc[m][n] = (f32x4){0.f, 0.f, 0.f, 0.f};

    // prologue: slices 0,1,2 staged
    STAGE_A(0) STAGE_B(0) STAGE_A(1) STAGE_B(1) STAGE_A(2) STAGE_B(2)

    for (int S = 0; S < 32; ++S) {
        if ((S & 1) == 0) {
            if (S < 30) { asm volatile("s_waitcnt vmcnt(4)" ::: "memory"); }
            else        { asm volatile("s_waitcnt vmcnt(0)" ::: "memory"); }
        }
        __builtin_amdgcn_s_barrier();   // all waves: slices S(,S+1) landed; prev slot reads done
        const ushort* As_ = Ar + (S & 3) * 8192 + lg * 2048;
        const ushort* Bs_ = Br + (S & 3) * 8192 + lg * 2048;
        // ---- phase 0: M-half 0 (reads A-lo + B), stage A(S+3) ----
        bf16x8 af[4], bv[4];
        #pragma unroll
        for (int j = 0; j < 4; ++j)
            af[j] = *(const bf16x8*)(As_ + (wr * 128 + j * 16 + l15) * 8);
        #pragma unroll
        for (int n = 0; n < 4; ++n)
            bv[n] = *(const bf16x8*)(Bs_ + (wc * 64 + n * 16 + l15) * 8);
        if (S <= 28) { STAGE_A(S + 3) }
        asm volatile("s_waitcnt lgkmcnt(0)" ::: "memory");
        __builtin_amdgcn_sched_barrier(0);
        __builtin_amdgcn_s_setprio(1);
        #pragma unroll
        for (int j = 0; j < 4; ++j)
            #pragma unroll
            for (int n = 0; n < 4; ++n)
                acc[j][n] = __builtin_amdgcn_mfma_f32_16x16x32_bf16(af[j], bv[n], acc[j][n], 0, 0, 0);
        __builtin_amdgcn_s_setprio(0);
        // ---- phase 1: M-half 1 (reads A-hi, reuse B), stage B(S+3) ----
        bf16x8 ag[4];
        #pragma unroll
        for (int j = 0; j < 4; ++j)
            ag[j] = *(const bf16x8*)(As_ + (wr * 128 + 64 + j * 16 + l15) * 8);
        if (S <= 28) { STAGE_B(S + 3) }
        asm volatile("s_waitcnt lgkmcnt(0)" ::: "memory");
        __builtin_amdgcn_sched_barrier(0);
        __builtin_amdgcn_s_setprio(1);
        #pragma unroll
        for (int j = 0; j < 4; ++j)
            #pragma unroll
            for (int n = 0; n < 4; ++n)
                acc[4 + j][n] = __builtin_amdgcn_mfma_f32_16x16x32_bf16(ag[j], bv[n], acc[4 + j][n], 0, 0, 0);
        __builtin_amdgcn_s_setprio(0);
    }
#undef STAGE_A
#undef STAGE_B

    if (col0 >= 1024 && col0 < 1536) {
        // gate-transform epilogue -> LOG decay gk (<= 0)
        const float base_ = A_log_base[0];
        const float s0 = softplus_f(A_log_delta[0]);
        const float s1 = softplus_f(A_log_delta[1]);
        const float s2 = softplus_f(A_log_delta[2]);
        const float c3 = s0 + s1 + s2;
        const float mg = c3 * (1.0f / 3.0f);
        #pragma unroll
        for (int m = 0; m < 8; ++m) {
            const int row = row0 + wr * 128 + m * 16 + lg * 4;
            float pf[4];
            #pragma unroll
            for (int r = 0; r < 4; ++r) {
                const int t = (row + r) & (Tn - 1);
                pf[r] = logf((float)(t + 1));
            }
            #pragma unroll
            for (int n = 0; n < 4; ++n) {
                const int dk = col0 - 1024 + wc * 64 + n * 16 + l15;   // 0..511
                const int h = dk >> 7;
                const float cumh = (h == 0) ? 0.f : (h == 1) ? s0 : (h == 2) ? s0 + s1 : c3;
                float alpha = (float)(3 - h) * (1.0f / 3.0f)
                            + (cumh - (float)h * mg) * (1.0f / LOG_T_REF_F);
                alpha = fminf(fmaxf(alpha, 0.0f), 1.0f);
                const float expA = expf(base_ + cumh);
                const float db = dt_bias[dk];
                #pragma unroll
                for (int r = 0; r < 4; ++r) {
                    const float p = expf(-alpha * pf[r]);
                    Eo[(size_t)(row + r) * KDn + dk] =
                        -expA * softplus_f(acc[m][n][r] + db) * p;
                }
            }
        }
    } else if (col0 >= 2560) {
        // g bf16
        #pragma unroll
        for (int m = 0; m < 8; ++m) {
            const int row = row0 + wr * 128 + m * 16 + lg * 4;
            #pragma unroll
            for (int n = 0; n < 4; ++n) {
                const int col = col0 - 2560 + wc * 64 + n * 16 + l15;
                #pragma unroll
                for (int r = 0; r < 4; ++r)
                    C2[(size_t)(row + r) * 1024 + col] = f2bf(acc[m][n][r]);
            }
        }
    } else if (col0 >= 1536) {
        // v fp32
        #pragma unroll
        for (int m = 0; m < 8; ++m) {
            const int row = row0 + wr * 128 + m * 16 + lg * 4;
            #pragma unroll
            for (int n = 0; n < 4; ++n) {
                const int col = col0 - 1536 + wc * 64 + n * 16 + l15;
                #pragma unroll
                for (int r = 0; r < 4; ++r)
                    Cv[(size_t)(row + r) * 1024 + col] = acc[m][n][r];
            }
        }
    } else {
        // qk fp32 (cols < 512 scaled by DK^-0.5)
        const float s = (col0 < 512) ? 0.08838834764831845f : 1.0f;
        #pragma unroll
        for (int m = 0; m < 8; ++m) {
            const int row = row0 + wr * 128 + m * 16 + lg * 4;
            #pragma unroll
            for (int n = 0; n < 4; ++n) {
                const int col = col0 + wc * 64 + n * 16 + l15;
                #pragma unroll
                for (int r = 0; r < 4; ++r)
                    C[(size_t)(row + r) * 1024 + col] = acc[m][n][r] * s;
            }
        }
    }
}

// ---------- 128x128 bf16 MFMA GEMM (output projection), BK=64, row-major XCD ----------
__global__ __launch_bounds__(256) void mm_out(const ushort* __restrict__ A,
    const ushort* __restrict__ Bw, float* __restrict__ C)
{
    __shared__ __align__(16) ushort As[8][128][8];
    __shared__ __align__(16) ushort Bs[8][128][8];
    const int raw = blockIdx.x;
    const int l = (raw & 7) * 64 + (raw >> 3);
    const int bx = l % 8, by = l / 8;
    const int tid = threadIdx.x;
    const int lane = tid & 63, w = tid >> 6;
    const int l15 = lane & 15, lg = lane >> 4;
    const int wr = (w >> 1) << 6, wc = (w & 1) << 6;
    const int row0 = by << 7, col0 = bx << 7;

    const ushort* A0 = A  + (size_t)(row0 + lane) * Dn + w * 8;
    const ushort* A1 = A  + (size_t)(row0 + 64 + lane) * Dn + w * 8;
    const ushort* B0 = Bw + (size_t)(col0 + lane) * Dn + w * 8;
    const ushort* B1 = Bw + (size_t)(col0 + 64 + lane) * Dn + w * 8;

    f32x4 acc[4][4];
    #pragma unroll
    for (int m = 0; m < 4; ++m)
        #pragma unroll
        for (int n = 0; n < 4; ++n)
            acc[m][n] = (f32x4){0.f, 0.f, 0.f, 0.f};

    for (int kt = 0; kt < Dn; kt += 64) {
        __syncthreads();
        gload16(A0 + kt,      &As[w][0][0]);
        gload16(A0 + kt + 32, &As[w + 4][0][0]);
        gload16(A1 + kt,      &As[w][64][0]);
        gload16(A1 + kt + 32, &As[w + 4][64][0]);
        gload16(B0 + kt,      &Bs[w][0][0]);
        gload16(B0 + kt + 32, &Bs[w + 4][0][0]);
        gload16(B1 + kt,      &Bs[w][64][0]);
        gload16(B1 + kt + 32, &Bs[w + 4][64][0]);
        __syncthreads();
        #pragma unroll
        for (int ks = 0; ks < 2; ++ks) {
            bf16x8 af[4], bv[4];
            #pragma unroll
            for (int m = 0; m < 4; ++m)
                af[m] = *(const bf16x8*)&As[ks * 4 + lg][wr + m * 16 + l15][0];
            #pragma unroll
            for (int n = 0; n < 4; ++n)
                bv[n] = *(const bf16x8*)&Bs[ks * 4 + lg][wc + n * 16 + l15][0];
            #pragma unroll
            for (int m = 0; m < 4; ++m)
                #pragma unroll
                for (int n = 0; n < 4; ++n)
                    acc[m][n] = __builtin_amdgcn_mfma_f32_16x16x32_bf16(af[m], bv[n], acc[m][n], 0, 0, 0);
        }
    }
    #pragma unroll
    for (int m = 0; m < 4; ++m) {
        const int row = row0 + wr + m * 16 + lg * 4;
        #pragma unroll
        for (int n = 0; n < 4; ++n) {
            const int col = col0 + wc + n * 16 + l15;
            #pragma unroll
            for (int r = 0; r < 4; ++r)
                C[(size_t)(row + r) * 1024 + col] = acc[m][n][r];
        }
    }
}

// ---------- chunked GLA, log-space attention form (all exp args <= 0) ----------
__global__ __launch_bounds__(1024) void gla_chunk(
    float* qk, const float* __restrict__ Gb, const float* __restrict__ vb,
    float* __restrict__ o, float* __restrict__ Sl, float* __restrict__ Dc)
{
    extern __shared__ __align__(16) char smem[];
    float*  g    = (float*)smem;
    ushort* qraw = (ushort*)(smem + 33792);
    ushort* kraw = (ushort*)(smem + 51200);
    ushort* Qb   = (ushort*)(smem + 68608);
    ushort* Koff = (ushort*)(smem + 86016);
    ushort* KhT  = (ushort*)(smem + 112128);
    ushort* At   = (ushort*)(smem + 130560);
    ushort* VT   = (ushort*)smem;            // overlay (phase >= 4)
    float*  qsum = (float*)(smem + 86016);   // phase-1 temp inside Koff region

    const int bid = blockIdx.x;
    const int co = bid >> 4, bh = bid & 15;
    const int b = bh >> 2, h = bh & 3;
    const int tid = threadIdx.x;
    const int w = tid >> 6, lane = tid & 63;
    const int l15 = lane & 15, lg = lane >> 4;
    const size_t rowbase = (size_t)(b * Tn + co * CLEN);

    // ---- phase 1: inclusive cumsum of gk -> g[64][132] ----
    float c16[16];
    int dk1 = 0, qr1 = 0;
    if (tid < 512) {
        dk1 = tid & 127; qr1 = tid >> 7;
        const float* gp = Gb + (rowbase + qr1 * 16) * 512 + h * 128 + dk1;
        float run = 0.f;
        #pragma unroll
        for (int s = 0; s < 16; ++s) { run += gp[(size_t)s * 512]; c16[s] = run; }
        qsum[qr1 * 128 + dk1] = run;
    }
    __syncthreads();
    if (tid < 512) {
        float pre = 0.f;
        for (int r = 0; r < qr1; ++r) pre += qsum[r * 128 + dk1];
        #pragma unroll
        for (int s = 0; s < 16; ++s) g[(qr1 * 16 + s) * 132 + dk1] = c16[s] + pre;
    }
    __syncthreads();

    // ---- phase 2: operand builds (all exp args <= 0) ----
    #pragma unroll
    for (int it = 0; it < 8; ++it) {
        const int idx = tid + it * 1024;
        const int t = idx >> 7, dk = idx & 127;
        const float gi = g[t * 132 + dk];
        const size_t qaddr = (rowbase + t) * 1024 + h * 128 + dk;
        const float qv = qk[qaddr];
        const float gr = (t < 16) ? 0.f : g[(16 * (t >> 4) - 1) * 132 + dk];
        Qb[t * 136 + dk] = f2bf(qv * __expf(gi - gr));
        qraw[t * 136 + dk] = f2bf(qv);
        qk[qaddr] = qv * __expf(gi);           // q~ in place (for fixup)
        const float kv = qk[qaddr + 512];
        kraw[t * 136 + dk] = f2bf(kv);
        KhT[dk * 72 + t] = f2bf(kv * __expf(g[63 * 132 + dk] - gi));
        if (t < 16) Koff[t * 136 + dk]        = f2bf(kv * __expf(g[15 * 132 + dk] - gi));
        if (t < 32) Koff[(16 + t) * 136 + dk] = f2bf(kv * __expf(g[31 * 132 + dk] - gi));
        if (t < 48) Koff[(48 + t) * 136 + dk] = f2bf(kv * __expf(g[47 * 132 + dk] - gi));
    }
    for (int i = tid; i < 2304; i += 1024) ((int*)At)[i] = 0;   // zero At
    if (tid < 128)
        Dc[(co * 16 + bh) * 128 + tid] = __expf(g[63 * 132 + tid]);
    __syncthreads();

    // ---- phase 3: QK -> At ----
    if (w < 6) {            // off-diagonal sub-chunk tiles (MFMA)
        const int Tt[6] = {16, 32, 32, 48, 48, 48};
        const int Ss[6] = { 0,  0, 16,  0, 16, 32};
        const int Kb[6] = { 0, 16, 16, 48, 48, 48};
        const int T = Tt[w], S = Ss[w], KB = Kb[w];
        f32x4 acc = (f32x4){0.f, 0.f, 0.f, 0.f};
        #pragma unroll
        for (int kk = 0; kk < 4; ++kk) {
            bf16x8 a  = *(const bf16x8*)&Qb[(T + l15) * 136 + kk * 32 + lg * 8];
            bf16x8 bb = *(const bf16x8*)&Koff[(KB + S + l15) * 136 + kk * 32 + lg * 8];
            acc = __builtin_amdgcn_mfma_f32_16x16x32_bf16(a, bb, acc, 0, 0, 0);
        }
        #pragma unroll
        for (int r = 0; r < 4; ++r)
            At[(T + lg * 4 + r) * 72 + S + l15] = f2bf(acc[r]);
    } else if (w < 14) {    // diagonal 16x16 blocks (scalar, masked, log-space)
        const int d = (w - 6) >> 1, hf = (w - 6) & 1;
        #pragma unroll
        for (int pp = 0; pp < 2; ++pp) {
            const int p = hf * 128 + pp * 64 + lane;
            const int i_ = p >> 4, j_ = p & 15;
            if (j_ <= i_) {
                const int ti = d * 16 + i_, tj = d * 16 + j_;
                float a = 0.f;
                for (int dk = 0; dk < 128; ++dk) {
                    const float qf = bf2f(qraw[ti * 136 + dk]);
                    const float kf = bf2f(kraw[tj * 136 + dk]);
                    a += qf * kf * __expf(g[ti * 132 + dk] - g[tj * 132 + dk]);
                }
                At[ti * 72 + tj] = f2bf(a);
            }
        }
    }
    __syncthreads();

    // ---- phase 4: V^T build (overlays dead g/qraw region) ----
    {
        const int dv4 = (tid & 63) * 4, tseg = tid >> 6;
        float4 vv[4];
        #pragma unroll
        for (int s = 0; s < 4; ++s)
            vv[s] = *(const float4*)&vb[(rowbase + tseg * 4 + s) * 1024 + h * 256 + dv4];
        const float* vf = (const float*)vv;
        #pragma unroll
        for (int c = 0; c < 4; ++c) {
            int lo = (unsigned)f2bf(vf[0 * 4 + c]) | ((unsigned)f2bf(vf[1 * 4 + c]) << 16);
            int hi = (unsigned)f2bf(vf[2 * 4 + c]) | ((unsigned)f2bf(vf[3 * 4 + c]) << 16);
            *(int2*)((char*)VT + (size_t)(dv4 + c) * 144 + tseg * 8) = make_int2(lo, hi);
        }
    }
    __syncthreads();

    // ---- phase 5: PV (o intra) + state S_local (MFMA) ----
    float* sp = Sl + (((size_t)co * 16 + bh) << 15);
    for (int id = w; id < 192; id += 16) {
        if (id < 64) {
            const int mt = id >> 4, nt = id & 15;
            f32x4 acc = (f32x4){0.f, 0.f, 0.f, 0.f};
            #pragma unroll
            for (int kk = 0; kk < 2; ++kk) {
                bf16x8 a  = *(const bf16x8*)&At[(mt * 16 + l15) * 72 + kk * 32 + lg * 8];
                bf16x8 bb = *(const bf16x8*)&VT[(nt * 16 + l15) * 72 + kk * 32 + lg * 8];
                acc = __builtin_amdgcn_mfma_f32_16x16x32_bf16(a, bb, acc, 0, 0, 0);
            }
            #pragma unroll
            for (int r = 0; r < 4; ++r)
                o[(rowbase + mt * 16 + lg * 4 + r) * 1024 + h * 256 + nt * 16 + l15] = acc[r];
        } else {
            const int sid = id - 64;
            const int mt = sid >> 4, nt = sid & 15;
            f32x4 acc = (f32x4){0.f, 0.f, 0.f, 0.f};
            #pragma unroll
            for (int kk = 0; kk < 2; ++kk) {
                bf16x8 a  = *(const bf16x8*)&KhT[(mt * 16 + l15) * 72 + kk * 32 + lg * 8];
                bf16x8 bb = *(const bf16x8*)&VT[(nt * 16 + l15) * 72 + kk * 32 + lg * 8];
                acc = __builtin_amdgcn_mfma_f32_16x16x32_bf16(a, bb, acc, 0, 0, 0);
            }
            #pragma unroll
            for (int r = 0; r < 4; ++r)
                sp[(size_t)(mt * 16 + lg * 4 + r) * 256 + nt * 16 + l15] = acc[r];
        }
    }
}

// sequential chunk combine (32 chunks): overwrite Sl[c] with chunk-c START state
__global__ __launch_bounds__(256) void combine(float* __restrict__ Sl,
                                               const float* __restrict__ Dc) {
    const int bh = blockIdx.y;
    const int e4 = blockIdx.x * 256 + threadIdx.x;
    const int dk = e4 >> 6;
    float4 s = make_float4(0.f, 0.f, 0.f, 0.f);
    #pragma unroll 4
    for (int c = 0; c < NCC; ++c) {
        float4* p = (float4*)(Sl + (((size_t)c * 16 + bh) << 15)) + e4;
        float4 local = *p;
        const float d = Dc[(c * 16 + bh) * DKn + dk];
        *p = s;
        s.x = s.x * d + local.x;  s.y = s.y * d + local.y;
        s.z = s.z * d + local.z;  s.w = s.w * d + local.w;
    }
}

// inter-chunk correction: o[t][dv] += sum_dk q~[t][dk] * S_start[dk][dv]
__global__ __launch_bounds__(256, 4) void fixup(const float* __restrict__ qt,
    const float* __restrict__ Sl, float* __restrict__ o)
{
    __shared__ __align__(16) float Aq[16][68];
    __shared__ __align__(16) float Bs[16][68];
    const int raw = blockIdx.x;
    const int l = (raw & 7) * 256 + (raw >> 3);
    const int dvt = l & 3, bh = (l >> 2) & 15, co = l >> 6;
    const int b = bh >> 2, h = bh & 3;
    const int tid = threadIdx.x;
    const int tx = tid & 15, ty = tid >> 4;
    const int t0 = co * CLEN;
    const int dv0 = dvt * 64;

    const float* qbase = qt + (size_t)(b * Tn + t0) * 1024 + h * 128;
    const float* sbase = Sl + (((size_t)co * 16 + bh) << 15) + dv0;

    float acc[4][4] = {};
    for (int k0 = 0; k0 < DKn; k0 += 16) {
        __syncthreads();
        {
            const int t = tid >> 2, kk4 = (tid & 3) << 2;
            float4 a = *(const float4*)&qbase[(size_t)t * 1024 + k0 + kk4];
            Aq[kk4 + 0][t] = a.x; Aq[kk4 + 1][t] = a.y;
            Aq[kk4 + 2][t] = a.z; Aq[kk4 + 3][t] = a.w;
        }
        {
            const int dk = tid >> 4, dvq = (tid & 15) << 2;
            *(float4*)&Bs[dk][dvq] = *(const float4*)&sbase[(size_t)(k0 + dk) * 256 + dvq];
        }
        __syncthreads();
        #pragma unroll
        for (int kk = 0; kk < 16; ++kk) {
            float4 a  = *(const float4*)&Aq[kk][ty * 4];
            float4 bv = *(const float4*)&Bs[kk][tx * 4];
            float ar[4] = {a.x, a.y, a.z, a.w};
            float br[4] = {bv.x, bv.y, bv.z, bv.w};
            #pragma unroll
            for (int i = 0; i < 4; ++i)
                #pragma unroll
                for (int j = 0; j < 4; ++j)
                    acc[i][j] += ar[i] * br[j];
        }
    }
    float* obp = o + (size_t)(b * Tn + t0) * 1024 + h * 256 + dv0;
    #pragma unroll
    for (int i = 0; i < 4; ++i) {
        float* row = obp + (size_t)(ty * 4 + i) * 1024 + tx * 4;
        float4 c = *(float4*)row;
        c.x += acc[i][0]; c.y += acc[i][1];
        c.z += acc[i][2]; c.w += acc[i][3];
        *(float4*)row = c;
    }
}

// ---------- RMSNorm + swish gate (g in bf16) -> bf16 ----------
__global__ __launch_bounds__(256) void rms_gate(const float* __restrict__ o,
    const ushort* __restrict__ gbf, const float* __restrict__ wt,
    ushort* __restrict__ obf)
{
    const int tid = threadIdx.x;
    const int w = tid >> 6, lane = tid & 63;
    const int row = blockIdx.x * 4 + w;
    const int n = row >> 2, h = row & 3;
    const size_t ob_base = (size_t)n * VDn + h * DVn + lane * 4;

    float4 o4 = *(const float4*)&o[ob_base];
    float ss = o4.x*o4.x + o4.y*o4.y + o4.z*o4.z + o4.w*o4.w;
    #pragma unroll
    for (int m = 1; m < 64; m <<= 1) ss += __shfl_xor(ss, m);
    const float r = rsqrtf(ss * (1.0f / DVn) + 1e-5f);

    ushort4 gu = *(const ushort4*)&gbf[ob_base];
    float gx = bf2f(gu.x), gy = bf2f(gu.y), gz = bf2f(gu.z), gw = bf2f(gu.w);
    float4 w4 = *(const float4*)&wt[h * DVn + lane * 4];
    ushort4 u;
    u.x = f2bf(o4.x * r * w4.x * (gx / (1.0f + expf(-gx))));
    u.y = f2bf(o4.y * r * w4.y * (gy / (1.0f + expf(-gy))));
    u.z = f2bf(o4.z * r * w4.z * (gz / (1.0f + expf(-gz))));
    u.w = f2bf(o4.w * r * w4.w * (gw / (1.0f + expf(-gw))));
    *(ushort4*)&obf[ob_base] = u;
}

extern "C" void kernel_launch(void* const* d_in, const int* in_sizes, int n_in,
                              void* d_out, int out_size, void* d_ws, size_t ws_size,
                              hipStream_t stream) {
    const float* hs          = (const float*)d_in[0];
    const float* Wq          = (const float*)d_in[1];
    const float* Wk          = (const float*)d_in[2];
    const float* Wv          = (const float*)d_in[3];
    const float* Wg          = (const float*)d_in[4];
    const float* Wa          = (const float*)d_in[5];
    const float* Wo          = (const float*)d_in[6];
    const float* A_log_base  = (const float*)d_in[7];
    const float* A_log_delta = (const float*)d_in[8];
    const float* dt_bias     = (const float*)d_in[9];
    const float* gnw         = (const float*)d_in[10];
    float* out = (float*)d_out;

    char* ws = (char*)d_ws;
    float*  qk   = (float*)(ws);                           // 32MB [8192][1024] q|k (q~ in place)
    float*  vb   = (float*)(ws + ((size_t)32  << 20));     // 32MB [8192][1024] v
    float*  Gbuf = (float*)(ws + ((size_t)64  << 20));     // 16MB [8192][512] log-decay
    float*  Sl   = (float*)(ws + ((size_t)80  << 20));     // 64MB [32][16][128][256]
    float*  ob   = (float*)(ws + ((size_t)144 << 20));     // 32MB [8192][1024]
    ushort* hsb  = (ushort*)(ws + ((size_t)144 << 20));    // 16MB overlay on ob
    ushort* gbf  = (ushort*)(ws + ((size_t)176 << 20));    // 16MB [8192][1024] g bf16
    ushort* Wcat = (ushort*)(ws + ((size_t)192 << 20));    //  7MB [3584][1024] q|k|a|v|g
    ushort* Wob  = (ushort*)(ws + ((size_t)199 << 20));    //  2MB
    float*  Dc   = (float*)(ws + ((size_t)201 << 20));     // 256KB [32*16][128]
    ushort* obf  = (ushort*)qk;                            // reuse qk after fixup

    // fused casts (weights concatenated q|k|a|v|g)
    CastArgs ca;
    ca.src[0] = hs; ca.src[1] = Wq; ca.src[2] = Wk; ca.src[3] = Wa;
    ca.src[4] = Wv; ca.src[5] = Wg; ca.src[6] = Wo;
    ca.dst[0] = hsb;
    ca.dst[1] = Wcat;
    ca.dst[2] = Wcat + (size_t)512 * 1024;
    ca.dst[3] = Wcat + (size_t)1024 * 1024;
    ca.dst[4] = Wcat + (size_t)1536 * 1024;
    ca.dst[5] = Wcat + (size_t)2560 * 1024;
    ca.dst[6] = Wob;
    const int n4s[7] = {NROWS * Dn / 4, KDn * Dn / 4, KDn * Dn / 4, KDn * Dn / 4,
                        VDn * Dn / 4, VDn * Dn / 4, VDn * Dn / 4};
    ca.cum[0] = 0;
    for (int i = 0; i < 7; ++i) ca.cum[i + 1] = ca.cum[i] + n4s[i];
    cast_all<<<2048, 256, 0, stream>>>(ca);

    // fused projection GEMM (256^2 sliced schedule, race-fixed): q|k, a->Gbuf, v, g
    (void)hipFuncSetAttribute((const void*)mm_big<14>,
                              hipFuncAttributeMaxDynamicSharedMemorySize, 131072);
    mm_big<14><<<448, 512, 131072, stream>>>(hsb, Wcat, qk, vb, gbf, Gbuf,
                                             dt_bias, A_log_base, A_log_delta);

    // chunked recurrence: log-space attention form
    (void)hipFuncSetAttribute((const void*)gla_chunk,
                              hipFuncAttributeMaxDynamicSharedMemorySize, 139776);
    gla_chunk<<<512, 1024, 139776, stream>>>(qk, Gbuf, vb, ob, Sl, Dc);
    combine<<<dim3(32, 16), 256, 0, stream>>>(Sl, Dc);
    fixup<<<2048, 256, 0, stream>>>(qk, Sl, ob);

    // epilogue
    rms_gate<<<NROWS * Hn / 4, 256, 0, stream>>>(ob, gbf, gnw, obf);
    mm_out<<<512, 256, 0, stream>>>(obf, Wob, out);
}

// Round 20
// 296.481 us; speedup vs baseline: 1.1734x; 1.0141x over previous
//
#include <hip/hip_runtime.h>
#include <math.h>

#define Bn   4
#define Tn   2048
#define Dn   1024
#define Hn   4
#define DKn  128
#define DVn  256
#define KDn  512
#define VDn  1024
#define NROWS 8192
#define NCC  32
#define CLEN 64
#define LOG_T_REF_F 6.2383246250395075f

using bf16x8 = __attribute__((ext_vector_type(8))) short;
using f32x4  = __attribute__((ext_vector_type(4))) float;

__device__ __forceinline__ float softplus_f(float x) {
    return fmaxf(x, 0.0f) + log1pf(expf(-fabsf(x)));
}
__device__ __forceinline__ ushort f2bf(float f) {
    unsigned u = __float_as_uint(f);
    u = (u + 0x7fffu + ((u >> 16) & 1u)) >> 16;
    return (ushort)u;
}
__device__ __forceinline__ float bf2f(ushort u) {
    return __uint_as_float((unsigned)u << 16);
}
__device__ __forceinline__ void gload16(const void* g, void* l) {
    __builtin_amdgcn_global_load_lds(
        (const __attribute__((address_space(1))) unsigned*)g,
        (__attribute__((address_space(3))) unsigned*)l, 16, 0, 0);
}

// ---------- fused fp32 -> bf16 cast over 7 segments ----------
struct CastArgs {
    const float* src[7];
    ushort* dst[7];
    int cum[8];
};
__global__ __launch_bounds__(256) void cast_all(CastArgs a) {
    const int total = a.cum[7];
    for (int i = blockIdx.x * 256 + threadIdx.x; i < total; i += gridDim.x * 256) {
        int s = 0;
        #pragma unroll
        for (int k = 1; k < 7; ++k) s += (i >= a.cum[k]) ? 1 : 0;
        const int off = i - a.cum[s];
        float4 v = *(const float4*)&a.src[s][(size_t)off * 4];
        ushort4 u;
        u.x = f2bf(v.x); u.y = f2bf(v.y); u.z = f2bf(v.z); u.w = f2bf(v.w);
        *(ushort4*)&a.dst[s][(size_t)off * 4] = u;
    }
}

// ---------- 256x256-tile fused projection GEMM, ring-2 / 2 blocks-per-CU ----------
// A[8192 x 1024] @ Wcat[3584 x 1024]^T. 512 threads, 8 waves (2Mx4N), wave owns 128x64.
// K in 32 slices of 32; ring of 2 slots/operand (16KB each, [4 ksub][256 row][8] bf16,
// conflict-free). LDS = 64KB -> 2 blocks/CU so cross-block waves cover barrier stalls.
// Per slice: [S<31 ? vmcnt(4) : vmcnt(0)] -> s_barrier (slice S visible everywhere) ->
// 12 ds_read frags -> lgkmcnt(0) -> s_barrier (slot S&1 fully read by all waves) ->
// STAGE(S+2) into slot S&1 -> setprio + 32 MFMA. Depth-1 prefetch, never drains mid-loop.
// Row-major in-XCD mapping. Accumulation order == R19 (bitwise-identical).
template<int NX>   // NX = N/256 = 14
__global__ __launch_bounds__(512) void mm_big(const ushort* __restrict__ A,
    const ushort* __restrict__ Bw, float* __restrict__ C,
    float* __restrict__ Cv, ushort* __restrict__ C2, float* __restrict__ Eo,
    const float* __restrict__ dt_bias, const float* __restrict__ A_log_base,
    const float* __restrict__ A_log_delta)
{
    extern __shared__ __align__(16) char smem2[];
    ushort* Ar = (ushort*)smem2;           // 2 slots x 8192 ushorts (16KB each)
    ushort* Br = Ar + 2 * 8192;
    const int raw = blockIdx.x;
    const int nwg = NX * 32;               // 448
    const int l = (raw & 7) * (nwg >> 3) + (raw >> 3);
    const int bx = l % NX, by = l / NX;    // row-major: A-panel per XCD
    const int tid = threadIdx.x;
    const int w = tid >> 6, lane = tid & 63;
    const int l15 = lane & 15, lg = lane >> 4;
    const int wr = w >> 2, wc = w & 3;
    const int row0 = by << 8, col0 = bx << 8;

    // staging assignment: wave w covers ksub = w>>1, rowgroups rg0, rg0+1 (rg0 = (w&1)*2)
    const int ksw = w >> 1;
    const int rg0 = (w & 1) * 2;
    const ushort* Asrc = A  + (size_t)(row0 + rg0 * 64 + lane) * Dn + ksw * 8;
    const ushort* Bsrc = Bw + (size_t)(col0 + rg0 * 64 + lane) * Dn + ksw * 8;
    ushort* Adst0 = Ar + (ksw * 256 + rg0 * 64) * 8;
    ushort* Bdst0 = Br + (ksw * 256 + rg0 * 64) * 8;

#define STAGE_A(S) { ushort* d_ = Adst0 + ((S) & 1) * 8192;                    \
    const ushort* s_ = Asrc + (size_t)(S) * 32;                                \
    gload16(s_, d_); gload16(s_ + (size_t)64 * Dn, d_ + 512); }
#define STAGE_B(S) { ushort* d_ = Bdst0 + ((S) & 1) * 8192;                    \
    const ushort* s_ = Bsrc + (size_t)(S) * 32;                                \
    gload16(s_, d_); gload16(s_ + (size_t)64 * Dn, d_ + 512); }

    f32x4 acc[8][4];
    #pragma unroll
    for (int m = 0; m < 8; ++m)
        #pragma unroll
        for (int n = 0; n < 4; ++n)
            acc[m][n] = (f32x4){0.f, 0.f, 0.f, 0.f};

    // prologue: slices 0,1 staged (8 loads/thread in flight)
    STAGE_A(0) STAGE_B(0) STAGE_A(1) STAGE_B(1)

    for (int S = 0; S < 32; ++S) {
        if (S < 31) { asm volatile("s_waitcnt vmcnt(4)" ::: "memory"); }
        else        { asm volatile("s_waitcnt vmcnt(0)" ::: "memory"); }
        __builtin_amdgcn_s_barrier();     // slice S landed in LDS, visible to all waves
        const ushort* As_ = Ar + (S & 1) * 8192 + lg * 2048;
        const ushort* Bs_ = Br + (S & 1) * 8192 + lg * 2048;
        bf16x8 af[8], bv[4];
        #pragma unroll
        for (int m = 0; m < 8; ++m)
            af[m] = *(const bf16x8*)(As_ + (wr * 128 + m * 16 + l15) * 8);
        #pragma unroll
        for (int n = 0; n < 4; ++n)
            bv[n] = *(const bf16x8*)(Bs_ + (wc * 64 + n * 16 + l15) * 8);
        asm volatile("s_waitcnt lgkmcnt(0)" ::: "memory");
        __builtin_amdgcn_sched_barrier(0);
        __builtin_amdgcn_s_barrier();     // all waves finished reading slot S&1
        if (S < 30) { STAGE_A(S + 2) STAGE_B(S + 2) }   // safe: slot free everywhere
        __builtin_amdgcn_s_setprio(1);
        #pragma unroll
        for (int m = 0; m < 8; ++m)
            #pragma unroll
            for (int n = 0; n < 4; ++n)
                acc[m][n] = __builtin_amdgcn_mfma_f32_16x16x32_bf16(af[m], bv[n], acc[m][n], 0, 0, 0);
        __builtin_amdgcn_s_setprio(0);
    }
#undef STAGE_A
#undef STAGE_B

    if (col0 >= 1024 && col0 < 1536) {
        // gate-transform epilogue -> LOG decay gk (<= 0)
        const float base_ = A_log_base[0];
        const float s0 = softplus_f(A_log_delta[0]);
        const float s1 = softplus_f(A_log_delta[1]);
        const float s2 = softplus_f(A_log_delta[2]);
        const float c3 = s0 + s1 + s2;
        const float mg = c3 * (1.0f / 3.0f);
        #pragma unroll
        for (int m = 0; m < 8; ++m) {
            const int row = row0 + wr * 128 + m * 16 + lg * 4;
            float pf[4];
            #pragma unroll
            for (int r = 0; r < 4; ++r) {
                const int t = (row + r) & (Tn - 1);
                pf[r] = logf((float)(t + 1));
            }
            #pragma unroll
            for (int n = 0; n < 4; ++n) {
                const int dk = col0 - 1024 + wc * 64 + n * 16 + l15;   // 0..511
                const int h = dk >> 7;
                const float cumh = (h == 0) ? 0.f : (h == 1) ? s0 : (h == 2) ? s0 + s1 : c3;
                float alpha = (float)(3 - h) * (1.0f / 3.0f)
                            + (cumh - (float)h * mg) * (1.0f / LOG_T_REF_F);
                alpha = fminf(fmaxf(alpha, 0.0f), 1.0f);
                const float expA = expf(base_ + cumh);
                const float db = dt_bias[dk];
                #pragma unroll
                for (int r = 0; r < 4; ++r) {
                    const float p = expf(-alpha * pf[r]);
                    Eo[(size_t)(row + r) * KDn + dk] =
                        -expA * softplus_f(acc[m][n][r] + db) * p;
                }
            }
        }
    } else if (col0 >= 2560) {
        // g bf16
        #pragma unroll
        for (int m = 0; m < 8; ++m) {
            const int row = row0 + wr * 128 + m * 16 + lg * 4;
            #pragma unroll
            for (int n = 0; n < 4; ++n) {
                const int col = col0 - 2560 + wc * 64 + n * 16 + l15;
                #pragma unroll
                for (int r = 0; r < 4; ++r)
                    C2[(size_t)(row + r) * 1024 + col] = f2bf(acc[m][n][r]);
            }
        }
    } else if (col0 >= 1536) {
        // v fp32
        #pragma unroll
        for (int m = 0; m < 8; ++m) {
            const int row = row0 + wr * 128 + m * 16 + lg * 4;
            #pragma unroll
            for (int n = 0; n < 4; ++n) {
                const int col = col0 - 1536 + wc * 64 + n * 16 + l15;
                #pragma unroll
                for (int r = 0; r < 4; ++r)
                    Cv[(size_t)(row + r) * 1024 + col] = acc[m][n][r];
            }
        }
    } else {
        // qk fp32 (cols < 512 scaled by DK^-0.5)
        const float s = (col0 < 512) ? 0.08838834764831845f : 1.0f;
        #pragma unroll
        for (int m = 0; m < 8; ++m) {
            const int row = row0 + wr * 128 + m * 16 + lg * 4;
            #pragma unroll
            for (int n = 0; n < 4; ++n) {
                const int col = col0 + wc * 64 + n * 16 + l15;
                #pragma unroll
                for (int r = 0; r < 4; ++r)
                    C[(size_t)(row + r) * 1024 + col] = acc[m][n][r] * s;
            }
        }
    }
}

// ---------- 128x128 bf16 MFMA GEMM (output projection), BK=64, row-major XCD ----------
__global__ __launch_bounds__(256) void mm_out(const ushort* __restrict__ A,
    const ushort* __restrict__ Bw, float* __restrict__ C)
{
    __shared__ __align__(16) ushort As[8][128][8];
    __shared__ __align__(16) ushort Bs[8][128][8];
    const int raw = blockIdx.x;
    const int l = (raw & 7) * 64 + (raw >> 3);
    const int bx = l % 8, by = l / 8;
    const int tid = threadIdx.x;
    const int lane = tid & 63, w = tid >> 6;
    const int l15 = lane & 15, lg = lane >> 4;
    const int wr = (w >> 1) << 6, wc = (w & 1) << 6;
    const int row0 = by << 7, col0 = bx << 7;

    const ushort* A0 = A  + (size_t)(row0 + lane) * Dn + w * 8;
    const ushort* A1 = A  + (size_t)(row0 + 64 + lane) * Dn + w * 8;
    const ushort* B0 = Bw + (size_t)(col0 + lane) * Dn + w * 8;
    const ushort* B1 = Bw + (size_t)(col0 + 64 + lane) * Dn + w * 8;

    f32x4 acc[4][4];
    #pragma unroll
    for (int m = 0; m < 4; ++m)
        #pragma unroll
        for (int n = 0; n < 4; ++n)
            acc[m][n] = (f32x4){0.f, 0.f, 0.f, 0.f};

    for (int kt = 0; kt < Dn; kt += 64) {
        __syncthreads();
        gload16(A0 + kt,      &As[w][0][0]);
        gload16(A0 + kt + 32, &As[w + 4][0][0]);
        gload16(A1 + kt,      &As[w][64][0]);
        gload16(A1 + kt + 32, &As[w + 4][64][0]);
        gload16(B0 + kt,      &Bs[w][0][0]);
        gload16(B0 + kt + 32, &Bs[w + 4][0][0]);
        gload16(B1 + kt,      &Bs[w][64][0]);
        gload16(B1 + kt + 32, &Bs[w + 4][64][0]);
        __syncthreads();
        #pragma unroll
        for (int ks = 0; ks < 2; ++ks) {
            bf16x8 af[4], bv[4];
            #pragma unroll
            for (int m = 0; m < 4; ++m)
                af[m] = *(const bf16x8*)&As[ks * 4 + lg][wr + m * 16 + l15][0];
            #pragma unroll
            for (int n = 0; n < 4; ++n)
                bv[n] = *(const bf16x8*)&Bs[ks * 4 + lg][wc + n * 16 + l15][0];
            #pragma unroll
            for (int m = 0; m < 4; ++m)
                #pragma unroll
                for (int n = 0; n < 4; ++n)
                    acc[m][n] = __builtin_amdgcn_mfma_f32_16x16x32_bf16(af[m], bv[n], acc[m][n], 0, 0, 0);
        }
    }
    #pragma unroll
    for (int m = 0; m < 4; ++m) {
        const int row = row0 + wr + m * 16 + lg * 4;
        #pragma unroll
        for (int n = 0; n < 4; ++n) {
            const int col = col0 + wc + n * 16 + l15;
            #pragma unroll
            for (int r = 0; r < 4; ++r)
                C[(size_t)(row + r) * 1024 + col] = acc[m][n][r];
        }
    }
}

// ---------- chunked GLA, log-space attention form (all exp args <= 0) ----------
__global__ __launch_bounds__(1024) void gla_chunk(
    float* qk, const float* __restrict__ Gb, const float* __restrict__ vb,
    float* __restrict__ o, float* __restrict__ Sl, float* __restrict__ Dc)
{
    extern __shared__ __align__(16) char smem[];
    float*  g    = (float*)smem;
    ushort* qraw = (ushort*)(smem + 33792);
    ushort* kraw = (ushort*)(smem + 51200);
    ushort* Qb   = (ushort*)(smem + 68608);
    ushort* Koff = (ushort*)(smem + 86016);
    ushort* KhT  = (ushort*)(smem + 112128);
    ushort* At   = (ushort*)(smem + 130560);
    ushort* VT   = (ushort*)smem;            // overlay (phase >= 4)
    float*  qsum = (float*)(smem + 86016);   // phase-1 temp inside Koff region

    const int bid = blockIdx.x;
    const int co = bid >> 4, bh = bid & 15;
    const int b = bh >> 2, h = bh & 3;
    const int tid = threadIdx.x;
    const int w = tid >> 6, lane = tid & 63;
    const int l15 = lane & 15, lg = lane >> 4;
    const size_t rowbase = (size_t)(b * Tn + co * CLEN);

    // ---- phase 1: inclusive cumsum of gk -> g[64][132] ----
    float c16[16];
    int dk1 = 0, qr1 = 0;
    if (tid < 512) {
        dk1 = tid & 127; qr1 = tid >> 7;
        const float* gp = Gb + (rowbase + qr1 * 16) * 512 + h * 128 + dk1;
        float run = 0.f;
        #pragma unroll
        for (int s = 0; s < 16; ++s) { run += gp[(size_t)s * 512]; c16[s] = run; }
        qsum[qr1 * 128 + dk1] = run;
    }
    __syncthreads();
    if (tid < 512) {
        float pre = 0.f;
        for (int r = 0; r < qr1; ++r) pre += qsum[r * 128 + dk1];
        #pragma unroll
        for (int s = 0; s < 16; ++s) g[(qr1 * 16 + s) * 132 + dk1] = c16[s] + pre;
    }
    __syncthreads();

    // ---- phase 2: operand builds (all exp args <= 0) ----
    #pragma unroll
    for (int it = 0; it < 8; ++it) {
        const int idx = tid + it * 1024;
        const int t = idx >> 7, dk = idx & 127;
        const float gi = g[t * 132 + dk];
        const size_t qaddr = (rowbase + t) * 1024 + h * 128 + dk;
        const float qv = qk[qaddr];
        const float gr = (t < 16) ? 0.f : g[(16 * (t >> 4) - 1) * 132 + dk];
        Qb[t * 136 + dk] = f2bf(qv * __expf(gi - gr));
        qraw[t * 136 + dk] = f2bf(qv);
        qk[qaddr] = qv * __expf(gi);           // q~ in place (for fixup)
        const float kv = qk[qaddr + 512];
        kraw[t * 136 + dk] = f2bf(kv);
        KhT[dk * 72 + t] = f2bf(kv * __expf(g[63 * 132 + dk] - gi));
        if (t < 16) Koff[t * 136 + dk]        = f2bf(kv * __expf(g[15 * 132 + dk] - gi));
        if (t < 32) Koff[(16 + t) * 136 + dk] = f2bf(kv * __expf(g[31 * 132 + dk] - gi));
        if (t < 48) Koff[(48 + t) * 136 + dk] = f2bf(kv * __expf(g[47 * 132 + dk] - gi));
    }
    for (int i = tid; i < 2304; i += 1024) ((int*)At)[i] = 0;   // zero At
    if (tid < 128)
        Dc[(co * 16 + bh) * 128 + tid] = __expf(g[63 * 132 + tid]);
    __syncthreads();

    // ---- phase 3: QK -> At ----
    if (w < 6) {            // off-diagonal sub-chunk tiles (MFMA)
        const int Tt[6] = {16, 32, 32, 48, 48, 48};
        const int Ss[6] = { 0,  0, 16,  0, 16, 32};
        const int Kb[6] = { 0, 16, 16, 48, 48, 48};
        const int T = Tt[w], S = Ss[w], KB = Kb[w];
        f32x4 acc = (f32x4){0.f, 0.f, 0.f, 0.f};
        #pragma unroll
        for (int kk = 0; kk < 4; ++kk) {
            bf16x8 a  = *(const bf16x8*)&Qb[(T + l15) * 136 + kk * 32 + lg * 8];
            bf16x8 bb = *(const bf16x8*)&Koff[(KB + S + l15) * 136 + kk * 32 + lg * 8];
            acc = __builtin_amdgcn_mfma_f32_16x16x32_bf16(a, bb, acc, 0, 0, 0);
        }
        #pragma unroll
        for (int r = 0; r < 4; ++r)
            At[(T + lg * 4 + r) * 72 + S + l15] = f2bf(acc[r]);
    } else if (w < 14) {    // diagonal 16x16 blocks (scalar, masked, log-space)
        const int d = (w - 6) >> 1, hf = (w - 6) & 1;
        #pragma unroll
        for (int pp = 0; pp < 2; ++pp) {
            const int p = hf * 128 + pp * 64 + lane;
            const int i_ = p >> 4, j_ = p & 15;
            if (j_ <= i_) {
                const int ti = d * 16 + i_, tj = d * 16 + j_;
                float a = 0.f;
                for (int dk = 0; dk < 128; ++dk) {
                    const float qf = bf2f(qraw[ti * 136 + dk]);
                    const float kf = bf2f(kraw[tj * 136 + dk]);
                    a += qf * kf * __expf(g[ti * 132 + dk] - g[tj * 132 + dk]);
                }
                At[ti * 72 + tj] = f2bf(a);
            }
        }
    }
    __syncthreads();

    // ---- phase 4: V^T build (overlays dead g/qraw region) ----
    {
        const int dv4 = (tid & 63) * 4, tseg = tid >> 6;
        float4 vv[4];
        #pragma unroll
        for (int s = 0; s < 4; ++s)
            vv[s] = *(const float4*)&vb[(rowbase + tseg * 4 + s) * 1024 + h * 256 + dv4];
        const float* vf = (const float*)vv;
        #pragma unroll
        for (int c = 0; c < 4; ++c) {
            int lo = (unsigned)f2bf(vf[0 * 4 + c]) | ((unsigned)f2bf(vf[1 * 4 + c]) << 16);
            int hi = (unsigned)f2bf(vf[2 * 4 + c]) | ((unsigned)f2bf(vf[3 * 4 + c]) << 16);
            *(int2*)((char*)VT + (size_t)(dv4 + c) * 144 + tseg * 8) = make_int2(lo, hi);
        }
    }
    __syncthreads();

    // ---- phase 5: PV (o intra) + state S_local (MFMA) ----
    float* sp = Sl + (((size_t)co * 16 + bh) << 15);
    for (int id = w; id < 192; id += 16) {
        if (id < 64) {
            const int mt = id >> 4, nt = id & 15;
            f32x4 acc = (f32x4){0.f, 0.f, 0.f, 0.f};
            #pragma unroll
            for (int kk = 0; kk < 2; ++kk) {
                bf16x8 a  = *(const bf16x8*)&At[(mt * 16 + l15) * 72 + kk * 32 + lg * 8];
                bf16x8 bb = *(const bf16x8*)&VT[(nt * 16 + l15) * 72 + kk * 32 + lg * 8];
                acc = __builtin_amdgcn_mfma_f32_16x16x32_bf16(a, bb, acc, 0, 0, 0);
            }
            #pragma unroll
            for (int r = 0; r < 4; ++r)
                o[(rowbase + mt * 16 + lg * 4 + r) * 1024 + h * 256 + nt * 16 + l15] = acc[r];
        } else {
            const int sid = id - 64;
            const int mt = sid >> 4, nt = sid & 15;
            f32x4 acc = (f32x4){0.f, 0.f, 0.f, 0.f};
            #pragma unroll
            for (int kk = 0; kk < 2; ++kk) {
                bf16x8 a  = *(const bf16x8*)&KhT[(mt * 16 + l15) * 72 + kk * 32 + lg * 8];
                bf16x8 bb = *(const bf16x8*)&VT[(nt * 16 + l15) * 72 + kk * 32 + lg * 8];
                acc = __builtin_amdgcn_mfma_f32_16x16x32_bf16(a, bb, acc, 0, 0, 0);
            }
            #pragma unroll
            for (int r = 0; r < 4; ++r)
                sp[(size_t)(mt * 16 + lg * 4 + r) * 256 + nt * 16 + l15] = acc[r];
        }
    }
}

// sequential chunk combine (32 chunks): overwrite Sl[c] with chunk-c START state
__global__ __launch_bounds__(256) void combine(float* __restrict__ Sl,
                                               const float* __restrict__ Dc) {
    const int bh = blockIdx.y;
    const int e4 = blockIdx.x * 256 + threadIdx.x;
    const int dk = e4 >> 6;
    float4 s = make_float4(0.f, 0.f, 0.f, 0.f);
    #pragma unroll 4
    for (int c = 0; c < NCC; ++c) {
        float4* p = (float4*)(Sl + (((size_t)c * 16 + bh) << 15)) + e4;
        float4 local = *p;
        const float d = Dc[(c * 16 + bh) * DKn + dk];
        *p = s;
        s.x = s.x * d + local.x;  s.y = s.y * d + local.y;
        s.z = s.z * d + local.z;  s.w = s.w * d + local.w;
    }
}

// inter-chunk correction: o[t][dv] += sum_dk q~[t][dk] * S_start[dk][dv]
__global__ __launch_bounds__(256, 4) void fixup(const float* __restrict__ qt,
    const float* __restrict__ Sl, float* __restrict__ o)
{
    __shared__ __align__(16) float Aq[16][68];
    __shared__ __align__(16) float Bs[16][68];
    const int raw = blockIdx.x;
    const int l = (raw & 7) * 256 + (raw >> 3);
    const int dvt = l & 3, bh = (l >> 2) & 15, co = l >> 6;
    const int b = bh >> 2, h = bh & 3;
    const int tid = threadIdx.x;
    const int tx = tid & 15, ty = tid >> 4;
    const int t0 = co * CLEN;
    const int dv0 = dvt * 64;

    const float* qbase = qt + (size_t)(b * Tn + t0) * 1024 + h * 128;
    const float* sbase = Sl + (((size_t)co * 16 + bh) << 15) + dv0;

    float acc[4][4] = {};
    for (int k0 = 0; k0 < DKn; k0 += 16) {
        __syncthreads();
        {
            const int t = tid >> 2, kk4 = (tid & 3) << 2;
            float4 a = *(const float4*)&qbase[(size_t)t * 1024 + k0 + kk4];
            Aq[kk4 + 0][t] = a.x; Aq[kk4 + 1][t] = a.y;
            Aq[kk4 + 2][t] = a.z; Aq[kk4 + 3][t] = a.w;
        }
        {
            const int dk = tid >> 4, dvq = (tid & 15) << 2;
            *(float4*)&Bs[dk][dvq] = *(const float4*)&sbase[(size_t)(k0 + dk) * 256 + dvq];
        }
        __syncthreads();
        #pragma unroll
        for (int kk = 0; kk < 16; ++kk) {
            float4 a  = *(const float4*)&Aq[kk][ty * 4];
            float4 bv = *(const float4*)&Bs[kk][tx * 4];
            float ar[4] = {a.x, a.y, a.z, a.w};
            float br[4] = {bv.x, bv.y, bv.z, bv.w};
            #pragma unroll
            for (int i = 0; i < 4; ++i)
                #pragma unroll
                for (int j = 0; j < 4; ++j)
                    acc[i][j] += ar[i] * br[j];
        }
    }
    float* obp = o + (size_t)(b * Tn + t0) * 1024 + h * 256 + dv0;
    #pragma unroll
    for (int i = 0; i < 4; ++i) {
        float* row = obp + (size_t)(ty * 4 + i) * 1024 + tx * 4;
        float4 c = *(float4*)row;
        c.x += acc[i][0]; c.y += acc[i][1];
        c.z += acc[i][2]; c.w += acc[i][3];
        *(float4*)row = c;
    }
}

// ---------- RMSNorm + swish gate (g in bf16) -> bf16 ----------
__global__ __launch_bounds__(256) void rms_gate(const float* __restrict__ o,
    const ushort* __restrict__ gbf, const float* __restrict__ wt,
    ushort* __restrict__ obf)
{
    const int tid = threadIdx.x;
    const int w = tid >> 6, lane = tid & 63;
    const int row = blockIdx.x * 4 + w;
    const int n = row >> 2, h = row & 3;
    const size_t ob_base = (size_t)n * VDn + h * DVn + lane * 4;

    float4 o4 = *(const float4*)&o[ob_base];
    float ss = o4.x*o4.x + o4.y*o4.y + o4.z*o4.z + o4.w*o4.w;
    #pragma unroll
    for (int m = 1; m < 64; m <<= 1) ss += __shfl_xor(ss, m);
    const float r = rsqrtf(ss * (1.0f / DVn) + 1e-5f);

    ushort4 gu = *(const ushort4*)&gbf[ob_base];
    float gx = bf2f(gu.x), gy = bf2f(gu.y), gz = bf2f(gu.z), gw = bf2f(gu.w);
    float4 w4 = *(const float4*)&wt[h * DVn + lane * 4];
    ushort4 u;
    u.x = f2bf(o4.x * r * w4.x * (gx / (1.0f + expf(-gx))));
    u.y = f2bf(o4.y * r * w4.y * (gy / (1.0f + expf(-gy))));
    u.z = f2bf(o4.z * r * w4.z * (gz / (1.0f + expf(-gz))));
    u.w = f2bf(o4.w * r * w4.w * (gw / (1.0f + expf(-gw))));
    *(ushort4*)&obf[ob_base] = u;
}

extern "C" void kernel_launch(void* const* d_in, const int* in_sizes, int n_in,
                              void* d_out, int out_size, void* d_ws, size_t ws_size,
                              hipStream_t stream) {
    const float* hs          = (const float*)d_in[0];
    const float* Wq          = (const float*)d_in[1];
    const float* Wk          = (const float*)d_in[2];
    const float* Wv          = (const float*)d_in[3];
    const float* Wg          = (const float*)d_in[4];
    const float* Wa          = (const float*)d_in[5];
    const float* Wo          = (const float*)d_in[6];
    const float* A_log_base  = (const float*)d_in[7];
    const float* A_log_delta = (const float*)d_in[8];
    const float* dt_bias     = (const float*)d_in[9];
    const float* gnw         = (const float*)d_in[10];
    float* out = (float*)d_out;

    char* ws = (char*)d_ws;
    float*  qk   = (float*)(ws);                           // 32MB [8192][1024] q|k (q~ in place)
    float*  vb   = (float*)(ws + ((size_t)32  << 20));     // 32MB [8192][1024] v
    float*  Gbuf = (float*)(ws + ((size_t)64  << 20));     // 16MB [8192][512] log-decay
    float*  Sl   = (float*)(ws + ((size_t)80  << 20));     // 64MB [32][16][128][256]
    float*  ob   = (float*)(ws + ((size_t)144 << 20));     // 32MB [8192][1024]
    ushort* hsb  = (ushort*)(ws + ((size_t)144 << 20));    // 16MB overlay on ob
    ushort* gbf  = (ushort*)(ws + ((size_t)176 << 20));    // 16MB [8192][1024] g bf16
    ushort* Wcat = (ushort*)(ws + ((size_t)192 << 20));    //  7MB [3584][1024] q|k|a|v|g
    ushort* Wob  = (ushort*)(ws + ((size_t)199 << 20));    //  2MB
    float*  Dc   = (float*)(ws + ((size_t)201 << 20));     // 256KB [32*16][128]
    ushort* obf  = (ushort*)qk;                            // reuse qk after fixup

    // fused casts (weights concatenated q|k|a|v|g)
    CastArgs ca;
    ca.src[0] = hs; ca.src[1] = Wq; ca.src[2] = Wk; ca.src[3] = Wa;
    ca.src[4] = Wv; ca.src[5] = Wg; ca.src[6] = Wo;
    ca.dst[0] = hsb;
    ca.dst[1] = Wcat;
    ca.dst[2] = Wcat + (size_t)512 * 1024;
    ca.dst[3] = Wcat + (size_t)1024 * 1024;
    ca.dst[4] = Wcat + (size_t)1536 * 1024;
    ca.dst[5] = Wcat + (size_t)2560 * 1024;
    ca.dst[6] = Wob;
    const int n4s[7] = {NROWS * Dn / 4, KDn * Dn / 4, KDn * Dn / 4, KDn * Dn / 4,
                        VDn * Dn / 4, VDn * Dn / 4, VDn * Dn / 4};
    ca.cum[0] = 0;
    for (int i = 0; i < 7; ++i) ca.cum[i + 1] = ca.cum[i] + n4s[i];
    cast_all<<<2048, 256, 0, stream>>>(ca);

    // fused projection GEMM (256^2 ring-2, 2 blocks/CU): q|k, a->Gbuf, v, g
    (void)hipFuncSetAttribute((const void*)mm_big<14>,
                              hipFuncAttributeMaxDynamicSharedMemorySize, 65536);
    mm_big<14><<<448, 512, 65536, stream>>>(hsb, Wcat, qk, vb, gbf, Gbuf,
                                            dt_bias, A_log_base, A_log_delta);

    // chunked recurrence: log-space attention form
    (void)hipFuncSetAttribute((const void*)gla_chunk,
                              hipFuncAttributeMaxDynamicSharedMemorySize, 139776);
    gla_chunk<<<512, 1024, 139776, stream>>>(qk, Gbuf, vb, ob, Sl, Dc);
    combine<<<dim3(32, 16), 256, 0, stream>>>(Sl, Dc);
    fixup<<<2048, 256, 0, stream>>>(qk, Sl, ob);

    // epilogue
    rms_gate<<<NROWS * Hn / 4, 256, 0, stream>>>(ob, gbf, gnw, obf);
    mm_out<<<512, 256, 0, stream>>>(obf, Wob, out);
}